// Round 15
// baseline (162.246 us; speedup 1.0000x reference)
//
#include <hip/hip_runtime.h>
#include <math.h>

#define T_DIM 2048
#define B_DIM 96
#define C_DIM 128
#define L_DIM 128
#define LOG2E 1.4426950408889634f
#define LN2 0.69314718055994531f
#define SMOOTH 0.1f
#define SENT (-(1 << 30))       // virgin lane frame (f32-exact power of 2)
#define PH 16
#define NPH 64                  // 64 phases x 16 steps per chain

// wave shift-right/left-by-1, 0-fill (proven helper class).
__device__ __forceinline__ float dpp_shr1_f(float x) {
  return __int_as_float(__builtin_amdgcn_update_dpp(
      0, __float_as_int(x), 0x138 /*WAVE_SR1*/, 0xF, 0xF, true));
}
__device__ __forceinline__ float dpp_shl1_f(float x) {
  return __int_as_float(__builtin_amdgcn_update_dpp(
      0, __float_as_int(x), 0x130 /*WAVE_SL1*/, 0xF, 0xF, true));
}

// ALPHA step — R9/R10/R14-proven math, verbatim (renamed state).
#define ASTEP(kk_) do {                                                      \
  const int k_ = (kk_);                                                      \
  const float pAv = afA[k_ & 3], pBv = afB[k_ & 3], pKv = afK[k_ & 3];       \
  {                                                                          \
    const int kn = k_ + 4;                                                   \
    const float* nr = (kn < PH) ? (ap0 + kn * C_DIM)                         \
                                : (ap1 + (kn - PH) * C_DIM);                 \
    afA[k_ & 3] = nr[tgA]; afB[k_ & 3] = nr[tgB]; afK[k_ & 3] = nr[0];       \
  }                                                                          \
  const float r3s = dpp_shr1_f(a3);                                          \
  const int   Es  = (int)dpp_shr1_f((float)aE);                              \
  const int   be  = (__float_as_int(r3s) >> 23) & 0xFF;                      \
  int diff = (be - 187) + (Es - aE);                                         \
  diff = (__float_as_int(r3s) != 0 && diff > 0) ? diff : 0;                  \
  a0 = ldexpf(a0, -diff); a1 = ldexpf(a1, -diff); a2 = ldexpf(a2, -diff);    \
  a3 = ldexpf(a3, -diff); a4 = ldexpf(a4, -diff);                            \
  aE += diff;                                                                \
  const float d3 = ldexpf(r3s, Es - aE);                                     \
  const float n0 = (a0 + d3) * pKv;                                          \
  const float n1 = __builtin_fmaf(skA, d3, a0 + a1) * pAv;                   \
  const float n2 = (a2 + a1) * pKv;                                          \
  const float n3 = __builtin_fmaf(skB, a1, a3 + a2) * pBv;                   \
  const float n4 = (a4 + a3) * pKv;                                          \
  a0 = n0; a1 = n1; a2 = n2; a3 = n3; a4 = n4;                               \
  if ((k_ & 3) == 3) {                                                       \
    const float m = fmaxf(fmaxf(fmaxf(a0, a1), fmaxf(a2, a3)), a4);          \
    const int sh2 = (m > 0.0f)                                               \
                      ? (187 - ((__float_as_int(m) >> 23) & 0xFF)) : 0;      \
    a0 = ldexpf(a0, sh2); a1 = ldexpf(a1, sh2); a2 = ldexpf(a2, sh2);        \
    a3 = ldexpf(a3, sh2); a4 = ldexpf(a4, sh2);                              \
    aE -= sh2;                                                               \
  }                                                                          \
} while (0)

// BETA step — R14-proven mirror math, verbatim (renamed state).
#define BSTEP(kk_) do {                                                      \
  const int k_ = (kk_);                                                      \
  const float pAv = bfA[k_ & 3], pBv = bfB[k_ & 3], pKv = bfK[k_ & 3];       \
  const float pNv = bfN[k_ & 3];                                             \
  {                                                                          \
    const int kn = k_ + 4;                                                   \
    const float* nr = (kn < PH) ? (bp0 + kn * C_DIM)                         \
                                : (bp1 + (kn - PH) * C_DIM);                 \
    bfA[k_ & 3] = nr[tgA]; bfB[k_ & 3] = nr[tgB]; bfK[k_ & 3] = nr[0];       \
    bfN[k_ & 3] = nr[tgAn];                                                  \
  }                                                                          \
  const float r1s = dpp_shl1_f(b1);                                          \
  const int   Es  = (int)dpp_shl1_f((float)bE);                              \
  const int   be  = (__float_as_int(r1s) >> 23) & 0xFF;                      \
  int diff = (be - 187) + (Es - bE);                                         \
  diff = (__float_as_int(r1s) != 0 && diff > 0) ? diff : 0;                  \
  b0 = ldexpf(b0, -diff); b1 = ldexpf(b1, -diff); b2 = ldexpf(b2, -diff);    \
  b3 = ldexpf(b3, -diff); b4 = ldexpf(b4, -diff);                            \
  bE += diff;                                                                \
  const float d5 = ldexpf(r1s, Es - bE);                                     \
  const float g0 = b0 * pKv, g1 = b1 * pAv, g2 = b2 * pKv;                   \
  const float g3 = b3 * pBv, g4 = b4 * pKv, g5 = d5 * pNv;                   \
  const float n0 = g0 + g1;                                                  \
  const float n1 = __builtin_fmaf(skAp, g3, g1 + g2);                        \
  const float n2 = g2 + g3;                                                  \
  const float n3 = __builtin_fmaf(skBp, g5, g3 + g4);                        \
  const float n4 = g4 + g5;                                                  \
  b0 = n0; b1 = n1; b2 = n2; b3 = n3; b4 = n4;                               \
  if ((k_ & 3) == 3) {                                                       \
    const float m = fmaxf(fmaxf(fmaxf(b0, b1), fmaxf(b2, b3)), b4);          \
    const int sh2 = (m > 0.0f)                                               \
                      ? (187 - ((__float_as_int(m) >> 23) & 0xFF)) : 0;      \
    b0 = ldexpf(b0, sh2); b1 = ldexpf(b1, sh2); b2 = ldexpf(b2, sh2);        \
    b3 = ldexpf(b3, sh2); b4 = ldexpf(b4, sh2);                              \
    bE -= sh2;                                                               \
  }                                                                          \
} while (0)

// One block (256 thr) per sample b.
//   wave 0   (consumer): BOTH recursions — alpha (t=1..1023) and beta
//     (rows 2047..1024) — interleaved per step. Two independent dependency
//     chains fill each other's stall slots on the SIMD. Combine (sum_s
//     alpha*beta) happens in-wave at the end.
//   waves1-3 (producer): stream both row ranges coalesced, pre-exponentiate
//     into two triple-buffered 16-row LDS rings; accumulate KL.
__global__ __launch_bounds__(256) void ctc_fused_kernel(
    const float* __restrict__ lp, const int* __restrict__ targets,
    const int* __restrict__ in_len, const int* __restrict__ tg_len,
    float* __restrict__ ws)
{
  const int tid = threadIdx.x;
  const int b = blockIdx.x;
  const size_t RSTR = (size_t)B_DIM * C_DIM;       // floats per t-row
  const int Tb = in_len[b];
  const int TbA = (Tb < 1024) ? Tb : 1024;
  const float* base = lp + (size_t)b * C_DIM;

  __shared__ float arows[3][PH][C_DIM];            // 24 KB alpha ring
  __shared__ float brows[3][PH][C_DIM];            // 24 KB beta ring
  __shared__ float klred[3];

  // consumer state (two disjoint chains)
  int tgA = 0, tgB = 0, tgAn = 0;
  float skA = 0.f, skB = 0.f, skAp = 0.f, skBp = 0.f;
  float a0 = 0.f, a1 = 0.f, a2 = 0.f, a3 = 0.f, a4 = 0.f;
  float b0 = 0.f, b1 = 0.f, b2 = 0.f, b3 = 0.f, b4 = 0.f;
  int aE = SENT, bE = SENT;
  float afA[4], afB[4], afK[4];
  float bfA[4], bfB[4], bfK[4], bfN[4];
  float klacc = 0.f;                               // producers only

  if (tid < 64) {
    const int l = tid;
    tgA = targets[b * L_DIM + 2 * l];
    tgB = targets[b * L_DIM + 2 * l + 1];
    const int nidx = (l < 63) ? (2 * l + 2) : (2 * l);
    tgAn = targets[b * L_DIM + nidx];
    skA  = (l > 0 && tgA != targets[b * L_DIM + 2 * l - 1]) ? 1.f : 0.f;
    skB  = (tgB != tgA) ? 1.f : 0.f;
    skAp = (tgB != tgA) ? 1.f : 0.f;
    skBp = (l < 63 && tgAn != tgB) ? 1.f : 0.f;
    if (l == 0) {                                  // alpha init (t=0)
      a0 = __builtin_amdgcn_exp2f(base[0]   * LOG2E);
      a1 = __builtin_amdgcn_exp2f(base[tgA] * LOG2E);
      aE = 0;
    }
    {                                              // beta init (row 2047)
      const int Lt = tg_len[b];
      const int s0 = 4 * l;
      b0 = (s0 == 2 * Lt || s0 == 2 * Lt - 1) ? 1.f : 0.f;
      b1 = (s0 + 1 == 2 * Lt || s0 + 1 == 2 * Lt - 1) ? 1.f : 0.f;
      b2 = (s0 + 2 == 2 * Lt || s0 + 2 == 2 * Lt - 1) ? 1.f : 0.f;
      b3 = (s0 + 3 == 2 * Lt || s0 + 3 == 2 * Lt - 1) ? 1.f : 0.f;
      b4 = (s0 + 4 == 2 * Lt || s0 + 4 == 2 * Lt - 1) ? 1.f : 0.f;
      bE = (b0 + b1 + b2 + b3 + b4 > 0.f) ? 0 : SENT;
    }
  } else {
    // prefill: alpha rows t=1..32 -> arows bufs 0,1; beta rows 2047..2016
    const int ptid = tid - 64;                     // 0..191
    #pragma unroll
    for (int i = 0; i < 6; ++i) {
      const int task = i * 192 + ptid;             // 32 rows x 32 float4
      if (task < 1024) {
        const int row = task >> 5;
        const int c4  = task & 31;
        const int t   = 1 + row;
        const float4 v = *(const float4*)(base + (size_t)t * RSTR + c4 * 4);
        float4 w;
        w.x = __builtin_amdgcn_exp2f(v.x * LOG2E);
        w.y = __builtin_amdgcn_exp2f(v.y * LOG2E);
        w.z = __builtin_amdgcn_exp2f(v.z * LOG2E);
        w.w = __builtin_amdgcn_exp2f(v.w * LOG2E);
        *(float4*)&arows[row >> 4][row & 15][c4 * 4] = w;
        if (t < Tb) {
          float s = v.x + v.y + v.z + v.w;
          if (c4 == 0) s -= v.x;
          klacc += s;
        }
      }
    }
    #pragma unroll
    for (int i = 0; i < 6; ++i) {
      const int task = i * 192 + ptid;
      if (task < 1024) {
        const int row = task >> 5;
        const int c4  = task & 31;
        const int t   = 2047 - row;
        const float4 v = *(const float4*)(base + (size_t)t * RSTR + c4 * 4);
        float4 w;
        w.x = __builtin_amdgcn_exp2f(v.x * LOG2E);
        w.y = __builtin_amdgcn_exp2f(v.y * LOG2E);
        w.z = __builtin_amdgcn_exp2f(v.z * LOG2E);
        w.w = __builtin_amdgcn_exp2f(v.w * LOG2E);
        *(float4*)&brows[row >> 4][row & 15][c4 * 4] = w;
        if (t < Tb) {
          float s = v.x + v.y + v.z + v.w;
          if (c4 == 0) s -= v.x;
          klacc += s;
        }
      }
    }
    if (ptid < 32 && 0 < Tb) {                     // row t=0 KL contribution
      const float4 v = *(const float4*)(base + ptid * 4);
      float s = v.x + v.y + v.z + v.w;
      if (ptid == 0) s -= v.x;
      klacc += s;
    }
  }
  __syncthreads();

  if (tid < 64) {                                  // pipeline prologues
    #pragma unroll
    for (int j = 0; j < 4; ++j) {
      afA[j] = arows[0][j][tgA]; afB[j] = arows[0][j][tgB];
      afK[j] = arows[0][j][0];
      bfA[j] = brows[0][j][tgA]; bfB[j] = brows[0][j][tgB];
      bfK[j] = brows[0][j][0];   bfN[j] = brows[0][j][tgAn];
    }
  }

  float* ap0 = &arows[0][0][0];
  float* ap1 = &arows[1][0][0];
  float* ap2 = &arows[2][0][0];
  float* bp0 = &brows[0][0][0];
  float* bp1 = &brows[1][0][0];
  float* bp2 = &brows[2][0][0];

  for (int p = 0; p < NPH; ++p) {
    if (tid < 64) {
      const bool aFast = (PH * p + PH + 1 <= TbA);
      const bool bFast = (2047 - PH * p < Tb);
      if (aFast && bFast) {
        // -------- FAST fused phase: both chains, branch-free --------
        #pragma unroll
        for (int k = 0; k < PH; ++k) { ASTEP(k); BSTEP(k); }
      } else {
        #pragma unroll
        for (int k = 0; k < PH; ++k) {
          const int t = 1 + PH * p + k;
          if (t < TbA) { ASTEP(k); }
        }
        #pragma unroll
        for (int k = 0; k < PH; ++k) {
          const int r = 2047 - PH * p - k;
          if (r < Tb) { BSTEP(k); }
        }
      }
    } else {
      // -------- producers: fill phase p+2 of both rings --------
      const int ptid = tid - 64;
      const int t0a = 33 + PH * p;
      if (t0a <= 1023) {
        #pragma unroll
        for (int i = 0; i < 3; ++i) {
          const int task = i * 192 + ptid;         // 16 rows x 32 float4
          if (task < 512) {
            const int row = task >> 5;
            const int c4  = task & 31;
            const int t   = t0a + row;
            if (t <= 1023) {
              const float4 v = *(const float4*)(base + (size_t)t * RSTR + c4 * 4);
              float4 w;
              w.x = __builtin_amdgcn_exp2f(v.x * LOG2E);
              w.y = __builtin_amdgcn_exp2f(v.y * LOG2E);
              w.z = __builtin_amdgcn_exp2f(v.z * LOG2E);
              w.w = __builtin_amdgcn_exp2f(v.w * LOG2E);
              *(float4*)&ap2[row * C_DIM + c4 * 4] = w;
              if (t < Tb) {
                float s = v.x + v.y + v.z + v.w;
                if (c4 == 0) s -= v.x;
                klacc += s;
              }
            }
          }
        }
      }
      const int t0b = 2015 - PH * p;
      if (t0b >= 1024) {
        #pragma unroll
        for (int i = 0; i < 3; ++i) {
          const int task = i * 192 + ptid;
          if (task < 512) {
            const int row = task >> 5;
            const int c4  = task & 31;
            const int t   = t0b - row;
            if (t >= 1024) {
              const float4 v = *(const float4*)(base + (size_t)t * RSTR + c4 * 4);
              float4 w;
              w.x = __builtin_amdgcn_exp2f(v.x * LOG2E);
              w.y = __builtin_amdgcn_exp2f(v.y * LOG2E);
              w.z = __builtin_amdgcn_exp2f(v.z * LOG2E);
              w.w = __builtin_amdgcn_exp2f(v.w * LOG2E);
              *(float4*)&bp2[row * C_DIM + c4 * 4] = w;
              if (t < Tb) {
                float s = v.x + v.y + v.z + v.w;
                if (c4 == 0) s -= v.x;
                klacc += s;
              }
            }
          }
        }
      }
    }
    __syncthreads();
    float* t1 = ap0; ap0 = ap1; ap1 = ap2; ap2 = t1;   // rotate rings
    float* t2 = bp0; bp0 = bp1; bp1 = bp2; bp2 = t2;
  }

  // ---------------- epilogue ----------------
  float ctc = 0.f;
  if (tid < 64) {
    const int l = tid;
    const float aEf = (float)aE, bEf = (float)bE;
    const float x0 = (__builtin_amdgcn_logf(a0) + aEf)
                   + (__builtin_amdgcn_logf(b0) + bEf);
    const float x1 = (__builtin_amdgcn_logf(a1) + aEf)
                   + (__builtin_amdgcn_logf(b1) + bEf);
    const float x2 = (__builtin_amdgcn_logf(a2) + aEf)
                   + (__builtin_amdgcn_logf(b2) + bEf);
    const float x3 = (__builtin_amdgcn_logf(a3) + aEf)
                   + (__builtin_amdgcn_logf(b3) + bEf);
    const float x4 = (l == 63) ? ((__builtin_amdgcn_logf(a4) + aEf)
                               + (__builtin_amdgcn_logf(b4) + bEf)) : -3.0e38f;
    float m = fmaxf(fmaxf(fmaxf(x0, x1), fmaxf(x2, x3)), x4);
    m = fmaxf(m, __shfl_xor(m, 1, 64));  m = fmaxf(m, __shfl_xor(m, 2, 64));
    m = fmaxf(m, __shfl_xor(m, 4, 64));  m = fmaxf(m, __shfl_xor(m, 8, 64));
    m = fmaxf(m, __shfl_xor(m, 16, 64)); m = fmaxf(m, __shfl_xor(m, 32, 64));
    const float ms = fmaxf(m, -1.0e37f);
    float s = __builtin_amdgcn_exp2f(x0 - ms) + __builtin_amdgcn_exp2f(x1 - ms)
            + __builtin_amdgcn_exp2f(x2 - ms) + __builtin_amdgcn_exp2f(x3 - ms)
            + __builtin_amdgcn_exp2f(x4 - ms);
    s += __shfl_xor(s, 1, 64);  s += __shfl_xor(s, 2, 64);
    s += __shfl_xor(s, 4, 64);  s += __shfl_xor(s, 8, 64);
    s += __shfl_xor(s, 16, 64); s += __shfl_xor(s, 32, 64);
    if (s > 0.f && m > -1.0e30f) {
      ctc = -((ms + __builtin_amdgcn_logf(s)) * LN2);
    }
  } else {
    float tot = klacc;
    tot += __shfl_xor(tot, 1, 64);  tot += __shfl_xor(tot, 2, 64);
    tot += __shfl_xor(tot, 4, 64);  tot += __shfl_xor(tot, 8, 64);
    tot += __shfl_xor(tot, 16, 64); tot += __shfl_xor(tot, 32, 64);
    if ((tid & 63) == 0) klred[(tid >> 6) - 1] = tot;
  }
  __syncthreads();
  if (tid == 0) {
    const float u    = 1.0f / (C_DIM - 1);
    const float logu = -4.8441870864585910f;       // log(1/127)
    const float kls  = klred[0] + klred[1] + klred[2];
    const float klmean = logu - u * kls / (float)Tb;
    ws[b] = (1.0f - SMOOTH) * ctc + SMOOTH * klmean;
  }
}

__global__ __launch_bounds__(128) void ctc_mean_kernel(
    const float* __restrict__ ws, float* __restrict__ out)
{
  __shared__ float red[128];
  const int tid = threadIdx.x;
  red[tid] = (tid < B_DIM) ? ws[tid] : 0.f;
  __syncthreads();
  for (int off = 64; off > 0; off >>= 1) {
    if (tid < off) red[tid] += red[tid + off];
    __syncthreads();
  }
  if (tid == 0) out[0] = red[0] / (float)B_DIM;
}

extern "C" void kernel_launch(void* const* d_in, const int* in_sizes, int n_in,
                              void* d_out, int out_size, void* d_ws, size_t ws_size,
                              hipStream_t stream) {
  const float* lp      = (const float*)d_in[0];
  const int* targets   = (const int*)d_in[1];
  const int* in_len    = (const int*)d_in[2];
  const int* tg_len    = (const int*)d_in[3];
  float* ws  = (float*)d_ws;
  float* out = (float*)d_out;

  hipLaunchKernelGGL(ctc_fused_kernel, dim3(B_DIM), dim3(256), 0, stream,
                     lp, targets, in_len, tg_len, ws);
  hipLaunchKernelGGL(ctc_mean_kernel, dim3(1), dim3(128), 0, stream,
                     ws, out);
}

// Round 16
// 161.910 us; speedup vs baseline: 1.0021x; 1.0021x over previous
//
#include <hip/hip_runtime.h>
#include <math.h>

#define T_DIM 2048
#define B_DIM 96
#define C_DIM 128
#define L_DIM 128
#define LOG2E 1.4426950408889634f
#define LN2 0.69314718055994531f
#define SMOOTH 0.1f
#define SENT (-(1 << 30))       // virgin lane frame (f32-exact power of 2)
#define PH 16
#define NPH 64                  // 64 phases x 16 steps per chain

// wave shift-right/left-by-1, 0-fill (proven helper class).
__device__ __forceinline__ float dpp_shr1_f(float x) {
  return __int_as_float(__builtin_amdgcn_update_dpp(
      0, __float_as_int(x), 0x138 /*WAVE_SR1*/, 0xF, 0xF, true));
}
__device__ __forceinline__ float dpp_shl1_f(float x) {
  return __int_as_float(__builtin_amdgcn_update_dpp(
      0, __float_as_int(x), 0x130 /*WAVE_SL1*/, 0xF, 0xF, true));
}

// ALPHA step — R9/R10/R14-proven math, verbatim; slots pinned via empty asm.
#define ASTEP(kk_) do {                                                      \
  const int k_ = (kk_);                                                      \
  const float pAv = afA[k_ & 3], pBv = afB[k_ & 3], pKv = afK[k_ & 3];       \
  {                                                                          \
    const int kn = k_ + 4;                                                   \
    const float* nr = (kn < PH) ? (ap0 + kn * C_DIM)                         \
                                : (ap1 + (kn - PH) * C_DIM);                 \
    afA[k_ & 3] = nr[tgA]; afB[k_ & 3] = nr[tgB]; afK[k_ & 3] = nr[0];       \
    asm("" : "+v"(afA[k_ & 3]), "+v"(afB[k_ & 3]), "+v"(afK[k_ & 3]));       \
  }                                                                          \
  const float r3s = dpp_shr1_f(a3);                                          \
  const int   Es  = (int)dpp_shr1_f((float)aE);                              \
  const int   be  = (__float_as_int(r3s) >> 23) & 0xFF;                      \
  int diff = (be - 187) + (Es - aE);                                         \
  diff = (__float_as_int(r3s) != 0 && diff > 0) ? diff : 0;                  \
  a0 = ldexpf(a0, -diff); a1 = ldexpf(a1, -diff); a2 = ldexpf(a2, -diff);    \
  a3 = ldexpf(a3, -diff); a4 = ldexpf(a4, -diff);                            \
  aE += diff;                                                                \
  const float d3 = ldexpf(r3s, Es - aE);                                     \
  const float n0 = (a0 + d3) * pKv;                                          \
  const float n1 = __builtin_fmaf(skA, d3, a0 + a1) * pAv;                   \
  const float n2 = (a2 + a1) * pKv;                                          \
  const float n3 = __builtin_fmaf(skB, a1, a3 + a2) * pBv;                   \
  const float n4 = (a4 + a3) * pKv;                                          \
  a0 = n0; a1 = n1; a2 = n2; a3 = n3; a4 = n4;                               \
  if ((k_ & 3) == 3) {                                                       \
    const float m = fmaxf(fmaxf(fmaxf(a0, a1), fmaxf(a2, a3)), a4);          \
    const int sh2 = (m > 0.0f)                                               \
                      ? (187 - ((__float_as_int(m) >> 23) & 0xFF)) : 0;      \
    a0 = ldexpf(a0, sh2); a1 = ldexpf(a1, sh2); a2 = ldexpf(a2, sh2);        \
    a3 = ldexpf(a3, sh2); a4 = ldexpf(a4, sh2);                              \
    aE -= sh2;                                                               \
  }                                                                          \
} while (0)

// BETA step — R14-proven mirror math, verbatim; slots pinned via empty asm.
#define BSTEP(kk_) do {                                                      \
  const int k_ = (kk_);                                                      \
  const float pAv = bfA[k_ & 3], pBv = bfB[k_ & 3], pKv = bfK[k_ & 3];       \
  const float pNv = bfN[k_ & 3];                                             \
  {                                                                          \
    const int kn = k_ + 4;                                                   \
    const float* nr = (kn < PH) ? (bp0 + kn * C_DIM)                         \
                                : (bp1 + (kn - PH) * C_DIM);                 \
    bfA[k_ & 3] = nr[tgA]; bfB[k_ & 3] = nr[tgB]; bfK[k_ & 3] = nr[0];       \
    bfN[k_ & 3] = nr[tgAn];                                                  \
    asm("" : "+v"(bfA[k_ & 3]), "+v"(bfB[k_ & 3]),                           \
             "+v"(bfK[k_ & 3]), "+v"(bfN[k_ & 3]));                          \
  }                                                                          \
  const float r1s = dpp_shl1_f(b1);                                          \
  const int   Es  = (int)dpp_shl1_f((float)bE);                              \
  const int   be  = (__float_as_int(r1s) >> 23) & 0xFF;                      \
  int diff = (be - 187) + (Es - bE);                                         \
  diff = (__float_as_int(r1s) != 0 && diff > 0) ? diff : 0;                  \
  b0 = ldexpf(b0, -diff); b1 = ldexpf(b1, -diff); b2 = ldexpf(b2, -diff);    \
  b3 = ldexpf(b3, -diff); b4 = ldexpf(b4, -diff);                            \
  bE += diff;                                                                \
  const float d5 = ldexpf(r1s, Es - bE);                                     \
  const float g0 = b0 * pKv, g1 = b1 * pAv, g2 = b2 * pKv;                   \
  const float g3 = b3 * pBv, g4 = b4 * pKv, g5 = d5 * pNv;                   \
  const float n0 = g0 + g1;                                                  \
  const float n1 = __builtin_fmaf(skAp, g3, g1 + g2);                        \
  const float n2 = g2 + g3;                                                  \
  const float n3 = __builtin_fmaf(skBp, g5, g3 + g4);                        \
  const float n4 = g4 + g5;                                                  \
  b0 = n0; b1 = n1; b2 = n2; b3 = n3; b4 = n4;                               \
  if ((k_ & 3) == 3) {                                                       \
    const float m = fmaxf(fmaxf(fmaxf(b0, b1), fmaxf(b2, b3)), b4);          \
    const int sh2 = (m > 0.0f)                                               \
                      ? (187 - ((__float_as_int(m) >> 23) & 0xFF)) : 0;      \
    b0 = ldexpf(b0, sh2); b1 = ldexpf(b1, sh2); b2 = ldexpf(b2, sh2);        \
    b3 = ldexpf(b3, sh2); b4 = ldexpf(b4, sh2);                              \
    bE -= sh2;                                                               \
  }                                                                          \
} while (0)

// One block (256 thr) per sample b.
//   wave 0   (consumer): BOTH recursions — alpha (t=1..1023) and beta
//     (rows 2047..1024) — interleaved per step; two independent dependency
//     chains fill each other's stall slots. launch_bounds(256,1) unlocks
//     the VGPR budget; asm pins keep the 28 prefetch slots live.
//   waves1-3 (producer): stream both row ranges coalesced, pre-exponentiate
//     into two triple-buffered 16-row LDS rings; accumulate KL.
__global__ __launch_bounds__(256, 1) void ctc_fused_kernel(
    const float* __restrict__ lp, const int* __restrict__ targets,
    const int* __restrict__ in_len, const int* __restrict__ tg_len,
    float* __restrict__ ws)
{
  const int tid = threadIdx.x;
  const int b = blockIdx.x;
  const size_t RSTR = (size_t)B_DIM * C_DIM;       // floats per t-row
  const int Tb = in_len[b];
  const int TbA = (Tb < 1024) ? Tb : 1024;
  const float* base = lp + (size_t)b * C_DIM;

  __shared__ float arows[3][PH][C_DIM];            // 24 KB alpha ring
  __shared__ float brows[3][PH][C_DIM];            // 24 KB beta ring
  __shared__ float klred[3];

  // consumer state (two disjoint chains)
  int tgA = 0, tgB = 0, tgAn = 0;
  float skA = 0.f, skB = 0.f, skAp = 0.f, skBp = 0.f;
  float a0 = 0.f, a1 = 0.f, a2 = 0.f, a3 = 0.f, a4 = 0.f;
  float b0 = 0.f, b1 = 0.f, b2 = 0.f, b3 = 0.f, b4 = 0.f;
  int aE = SENT, bE = SENT;
  float afA[4], afB[4], afK[4];
  float bfA[4], bfB[4], bfK[4], bfN[4];
  float klacc = 0.f;                               // producers only

  if (tid < 64) {
    const int l = tid;
    tgA = targets[b * L_DIM + 2 * l];
    tgB = targets[b * L_DIM + 2 * l + 1];
    const int nidx = (l < 63) ? (2 * l + 2) : (2 * l);
    tgAn = targets[b * L_DIM + nidx];
    skA  = (l > 0 && tgA != targets[b * L_DIM + 2 * l - 1]) ? 1.f : 0.f;
    skB  = (tgB != tgA) ? 1.f : 0.f;
    skAp = (tgB != tgA) ? 1.f : 0.f;
    skBp = (l < 63 && tgAn != tgB) ? 1.f : 0.f;
    if (l == 0) {                                  // alpha init (t=0)
      a0 = __builtin_amdgcn_exp2f(base[0]   * LOG2E);
      a1 = __builtin_amdgcn_exp2f(base[tgA] * LOG2E);
      aE = 0;
    }
    {                                              // beta init (row 2047)
      const int Lt = tg_len[b];
      const int s0 = 4 * l;
      b0 = (s0 == 2 * Lt || s0 == 2 * Lt - 1) ? 1.f : 0.f;
      b1 = (s0 + 1 == 2 * Lt || s0 + 1 == 2 * Lt - 1) ? 1.f : 0.f;
      b2 = (s0 + 2 == 2 * Lt || s0 + 2 == 2 * Lt - 1) ? 1.f : 0.f;
      b3 = (s0 + 3 == 2 * Lt || s0 + 3 == 2 * Lt - 1) ? 1.f : 0.f;
      b4 = (s0 + 4 == 2 * Lt || s0 + 4 == 2 * Lt - 1) ? 1.f : 0.f;
      bE = (b0 + b1 + b2 + b3 + b4 > 0.f) ? 0 : SENT;
    }
  } else {
    // prefill: alpha rows t=1..32 -> arows bufs 0,1; beta rows 2047..2016
    const int ptid = tid - 64;                     // 0..191
    #pragma unroll
    for (int i = 0; i < 6; ++i) {
      const int task = i * 192 + ptid;             // 32 rows x 32 float4
      if (task < 1024) {
        const int row = task >> 5;
        const int c4  = task & 31;
        const int t   = 1 + row;
        const float4 v = *(const float4*)(base + (size_t)t * RSTR + c4 * 4);
        float4 w;
        w.x = __builtin_amdgcn_exp2f(v.x * LOG2E);
        w.y = __builtin_amdgcn_exp2f(v.y * LOG2E);
        w.z = __builtin_amdgcn_exp2f(v.z * LOG2E);
        w.w = __builtin_amdgcn_exp2f(v.w * LOG2E);
        *(float4*)&arows[row >> 4][row & 15][c4 * 4] = w;
        if (t < Tb) {
          float s = v.x + v.y + v.z + v.w;
          if (c4 == 0) s -= v.x;
          klacc += s;
        }
      }
    }
    #pragma unroll
    for (int i = 0; i < 6; ++i) {
      const int task = i * 192 + ptid;
      if (task < 1024) {
        const int row = task >> 5;
        const int c4  = task & 31;
        const int t   = 2047 - row;
        const float4 v = *(const float4*)(base + (size_t)t * RSTR + c4 * 4);
        float4 w;
        w.x = __builtin_amdgcn_exp2f(v.x * LOG2E);
        w.y = __builtin_amdgcn_exp2f(v.y * LOG2E);
        w.z = __builtin_amdgcn_exp2f(v.z * LOG2E);
        w.w = __builtin_amdgcn_exp2f(v.w * LOG2E);
        *(float4*)&brows[row >> 4][row & 15][c4 * 4] = w;
        if (t < Tb) {
          float s = v.x + v.y + v.z + v.w;
          if (c4 == 0) s -= v.x;
          klacc += s;
        }
      }
    }
    if (ptid < 32 && 0 < Tb) {                     // row t=0 KL contribution
      const float4 v = *(const float4*)(base + ptid * 4);
      float s = v.x + v.y + v.z + v.w;
      if (ptid == 0) s -= v.x;
      klacc += s;
    }
  }
  __syncthreads();

  if (tid < 64) {                                  // pipeline prologues
    #pragma unroll
    for (int j = 0; j < 4; ++j) {
      afA[j] = arows[0][j][tgA]; afB[j] = arows[0][j][tgB];
      afK[j] = arows[0][j][0];
      bfA[j] = brows[0][j][tgA]; bfB[j] = brows[0][j][tgB];
      bfK[j] = brows[0][j][0];   bfN[j] = brows[0][j][tgAn];
      asm("" : "+v"(afA[j]), "+v"(afB[j]), "+v"(afK[j]),
               "+v"(bfA[j]), "+v"(bfB[j]), "+v"(bfK[j]), "+v"(bfN[j]));
    }
  }

  float* ap0 = &arows[0][0][0];
  float* ap1 = &arows[1][0][0];
  float* ap2 = &arows[2][0][0];
  float* bp0 = &brows[0][0][0];
  float* bp1 = &brows[1][0][0];
  float* bp2 = &brows[2][0][0];

  for (int p = 0; p < NPH; ++p) {
    if (tid < 64) {
      const bool aFast = (PH * p + PH + 1 <= TbA);
      const bool bFast = (2047 - PH * p < Tb);
      if (aFast && bFast) {
        // -------- FAST fused phase: both chains, branch-free --------
        #pragma unroll
        for (int k = 0; k < PH; ++k) { ASTEP(k); BSTEP(k); }
      } else {
        #pragma unroll
        for (int k = 0; k < PH; ++k) {
          const int t = 1 + PH * p + k;
          if (t < TbA) { ASTEP(k); }
        }
        #pragma unroll
        for (int k = 0; k < PH; ++k) {
          const int r = 2047 - PH * p - k;
          if (r < Tb) { BSTEP(k); }
        }
      }
    } else {
      // -------- producers: fill phase p+2 of both rings --------
      const int ptid = tid - 64;
      const int t0a = 33 + PH * p;
      if (t0a <= 1023) {
        #pragma unroll
        for (int i = 0; i < 3; ++i) {
          const int task = i * 192 + ptid;         // 16 rows x 32 float4
          if (task < 512) {
            const int row = task >> 5;
            const int c4  = task & 31;
            const int t   = t0a + row;
            if (t <= 1023) {
              const float4 v = *(const float4*)(base + (size_t)t * RSTR + c4 * 4);
              float4 w;
              w.x = __builtin_amdgcn_exp2f(v.x * LOG2E);
              w.y = __builtin_amdgcn_exp2f(v.y * LOG2E);
              w.z = __builtin_amdgcn_exp2f(v.z * LOG2E);
              w.w = __builtin_amdgcn_exp2f(v.w * LOG2E);
              *(float4*)&ap2[row * C_DIM + c4 * 4] = w;
              if (t < Tb) {
                float s = v.x + v.y + v.z + v.w;
                if (c4 == 0) s -= v.x;
                klacc += s;
              }
            }
          }
        }
      }
      const int t0b = 2015 - PH * p;
      if (t0b >= 1024) {
        #pragma unroll
        for (int i = 0; i < 3; ++i) {
          const int task = i * 192 + ptid;
          if (task < 512) {
            const int row = task >> 5;
            const int c4  = task & 31;
            const int t   = t0b - row;
            if (t >= 1024) {
              const float4 v = *(const float4*)(base + (size_t)t * RSTR + c4 * 4);
              float4 w;
              w.x = __builtin_amdgcn_exp2f(v.x * LOG2E);
              w.y = __builtin_amdgcn_exp2f(v.y * LOG2E);
              w.z = __builtin_amdgcn_exp2f(v.z * LOG2E);
              w.w = __builtin_amdgcn_exp2f(v.w * LOG2E);
              *(float4*)&bp2[row * C_DIM + c4 * 4] = w;
              if (t < Tb) {
                float s = v.x + v.y + v.z + v.w;
                if (c4 == 0) s -= v.x;
                klacc += s;
              }
            }
          }
        }
      }
    }
    __syncthreads();
    float* t1 = ap0; ap0 = ap1; ap1 = ap2; ap2 = t1;   // rotate rings
    float* t2 = bp0; bp0 = bp1; bp1 = bp2; bp2 = t2;
  }

  // ---------------- epilogue ----------------
  float ctc = 0.f;
  if (tid < 64) {
    const int l = tid;
    const float aEf = (float)aE, bEf = (float)bE;
    const float x0 = (__builtin_amdgcn_logf(a0) + aEf)
                   + (__builtin_amdgcn_logf(b0) + bEf);
    const float x1 = (__builtin_amdgcn_logf(a1) + aEf)
                   + (__builtin_amdgcn_logf(b1) + bEf);
    const float x2 = (__builtin_amdgcn_logf(a2) + aEf)
                   + (__builtin_amdgcn_logf(b2) + bEf);
    const float x3 = (__builtin_amdgcn_logf(a3) + aEf)
                   + (__builtin_amdgcn_logf(b3) + bEf);
    const float x4 = (l == 63) ? ((__builtin_amdgcn_logf(a4) + aEf)
                               + (__builtin_amdgcn_logf(b4) + bEf)) : -3.0e38f;
    float m = fmaxf(fmaxf(fmaxf(x0, x1), fmaxf(x2, x3)), x4);
    m = fmaxf(m, __shfl_xor(m, 1, 64));  m = fmaxf(m, __shfl_xor(m, 2, 64));
    m = fmaxf(m, __shfl_xor(m, 4, 64));  m = fmaxf(m, __shfl_xor(m, 8, 64));
    m = fmaxf(m, __shfl_xor(m, 16, 64)); m = fmaxf(m, __shfl_xor(m, 32, 64));
    const float ms = fmaxf(m, -1.0e37f);
    float s = __builtin_amdgcn_exp2f(x0 - ms) + __builtin_amdgcn_exp2f(x1 - ms)
            + __builtin_amdgcn_exp2f(x2 - ms) + __builtin_amdgcn_exp2f(x3 - ms)
            + __builtin_amdgcn_exp2f(x4 - ms);
    s += __shfl_xor(s, 1, 64);  s += __shfl_xor(s, 2, 64);
    s += __shfl_xor(s, 4, 64);  s += __shfl_xor(s, 8, 64);
    s += __shfl_xor(s, 16, 64); s += __shfl_xor(s, 32, 64);
    if (s > 0.f && m > -1.0e30f) {
      ctc = -((ms + __builtin_amdgcn_logf(s)) * LN2);
    }
  } else {
    float tot = klacc;
    tot += __shfl_xor(tot, 1, 64);  tot += __shfl_xor(tot, 2, 64);
    tot += __shfl_xor(tot, 4, 64);  tot += __shfl_xor(tot, 8, 64);
    tot += __shfl_xor(tot, 16, 64); tot += __shfl_xor(tot, 32, 64);
    if ((tid & 63) == 0) klred[(tid >> 6) - 1] = tot;
  }
  __syncthreads();
  if (tid == 0) {
    const float u    = 1.0f / (C_DIM - 1);
    const float logu = -4.8441870864585910f;       // log(1/127)
    const float kls  = klred[0] + klred[1] + klred[2];
    const float klmean = logu - u * kls / (float)Tb;
    ws[b] = (1.0f - SMOOTH) * ctc + SMOOTH * klmean;
  }
}

__global__ __launch_bounds__(128) void ctc_mean_kernel(
    const float* __restrict__ ws, float* __restrict__ out)
{
  __shared__ float red[128];
  const int tid = threadIdx.x;
  red[tid] = (tid < B_DIM) ? ws[tid] : 0.f;
  __syncthreads();
  for (int off = 64; off > 0; off >>= 1) {
    if (tid < off) red[tid] += red[tid + off];
    __syncthreads();
  }
  if (tid == 0) out[0] = red[0] / (float)B_DIM;
}

extern "C" void kernel_launch(void* const* d_in, const int* in_sizes, int n_in,
                              void* d_out, int out_size, void* d_ws, size_t ws_size,
                              hipStream_t stream) {
  const float* lp      = (const float*)d_in[0];
  const int* targets   = (const int*)d_in[1];
  const int* in_len    = (const int*)d_in[2];
  const int* tg_len    = (const int*)d_in[3];
  float* ws  = (float*)d_ws;
  float* out = (float*)d_out;

  hipLaunchKernelGGL(ctc_fused_kernel, dim3(B_DIM), dim3(256), 0, stream,
                     lp, targets, in_len, tg_len, ws);
  hipLaunchKernelGGL(ctc_mean_kernel, dim3(1), dim3(128), 0, stream,
                     ws, out);
}

// Round 17
// 139.872 us; speedup vs baseline: 1.1600x; 1.1576x over previous
//
#include <hip/hip_runtime.h>
#include <math.h>

#define T_DIM 2048
#define B_DIM 96
#define C_DIM 128
#define L_DIM 128
#define LOG2E 1.4426950408889634f
#define LN2 0.69314718055994531f
#define SMOOTH 0.1f
#define SENT (-(1 << 30))       // virgin lane frame (f32-exact power of 2)
#define NPH 32                  // 32 phases x 32 steps per chain

// ws layout (floats)
#define AOFF 0                  // 96*257 alpha log2 values at t=1023
#define BOFF 24672              // 96*257 beta  log2 values at t=1023
#define KLA  49344              // 96 partial KL (rows 0..1023)
#define KLB  49440              // 96 partial KL (rows 1024..2047)
#define LOSS 49536              // 96 per-sample losses

__device__ __forceinline__ float dpp_shr1_f(float x) {
  return __int_as_float(__builtin_amdgcn_update_dpp(
      0, __float_as_int(x), 0x138 /*WAVE_SR1*/, 0xF, 0xF, true));
}
__device__ __forceinline__ float dpp_shl1_f(float x) {
  return __int_as_float(__builtin_amdgcn_update_dpp(
      0, __float_as_int(x), 0x130 /*WAVE_SL1*/, 0xF, 0xF, true));
}

// R9/R10/R14-proven ALPHA step math (verbatim), depth-4 prefetch.
#define ALPHA_STEP(kk_) do {                                                 \
  const int k_ = (kk_);                                                      \
  const float pAv = fA[k_ & 3], pBv = fB[k_ & 3], pKv = fK[k_ & 3];          \
  {                                                                          \
    const int kn = k_ + 4;                                                   \
    const float* nr = (kn < 32) ? (pc + kn * C_DIM)                          \
                                : (pn + (kn - 32) * C_DIM);                  \
    fA[k_ & 3] = nr[tgA]; fB[k_ & 3] = nr[tgB]; fK[k_ & 3] = nr[0];          \
  }                                                                          \
  const float r3s = dpp_shr1_f(r3);                                          \
  const int   Es  = (int)dpp_shr1_f((float)E);                               \
  const int   be  = (__float_as_int(r3s) >> 23) & 0xFF;                      \
  int diff = (be - 187) + (Es - E);                                          \
  diff = (__float_as_int(r3s) != 0 && diff > 0) ? diff : 0;                  \
  r0 = ldexpf(r0, -diff); r1 = ldexpf(r1, -diff); r2 = ldexpf(r2, -diff);    \
  r3 = ldexpf(r3, -diff); r4 = ldexpf(r4, -diff);                            \
  E += diff;                                                                 \
  const float d3 = ldexpf(r3s, Es - E);                                      \
  const float n0 = (r0 + d3) * pKv;                                          \
  const float n1 = __builtin_fmaf(skA, d3, r0 + r1) * pAv;                   \
  const float n2 = (r2 + r1) * pKv;                                          \
  const float n3 = __builtin_fmaf(skB, r1, r3 + r2) * pBv;                   \
  const float n4 = (r4 + r3) * pKv;                                          \
  r0 = n0; r1 = n1; r2 = n2; r3 = n3; r4 = n4;                               \
  if ((k_ & 3) == 3) {                                                       \
    const float m = fmaxf(fmaxf(fmaxf(r0, r1), fmaxf(r2, r3)), r4);          \
    const int sh2 = (m > 0.0f)                                               \
                      ? (187 - ((__float_as_int(m) >> 23) & 0xFF)) : 0;      \
    r0 = ldexpf(r0, sh2); r1 = ldexpf(r1, sh2); r2 = ldexpf(r2, sh2);        \
    r3 = ldexpf(r3, sh2); r4 = ldexpf(r4, sh2);                              \
    E -= sh2;                                                                \
  }                                                                          \
} while (0)

// R14-proven BETA step math (verbatim mirror).
#define BETA_STEP(kk_) do {                                                  \
  const int k_ = (kk_);                                                      \
  const float pAv = fA[k_ & 3], pBv = fB[k_ & 3], pKv = fK[k_ & 3];          \
  const float pNv = fN[k_ & 3];                                              \
  {                                                                          \
    const int kn = k_ + 4;                                                   \
    const float* nr = (kn < 32) ? (pc + kn * C_DIM)                          \
                                : (pn + (kn - 32) * C_DIM);                  \
    fA[k_ & 3] = nr[tgA]; fB[k_ & 3] = nr[tgB]; fK[k_ & 3] = nr[0];          \
    fN[k_ & 3] = nr[tgAn];                                                   \
  }                                                                          \
  const float r1s = dpp_shl1_f(r1);                                          \
  const int   Es  = (int)dpp_shl1_f((float)E);                               \
  const int   be  = (__float_as_int(r1s) >> 23) & 0xFF;                      \
  int diff = (be - 187) + (Es - E);                                          \
  diff = (__float_as_int(r1s) != 0 && diff > 0) ? diff : 0;                  \
  r0 = ldexpf(r0, -diff); r1 = ldexpf(r1, -diff); r2 = ldexpf(r2, -diff);    \
  r3 = ldexpf(r3, -diff); r4 = ldexpf(r4, -diff);                            \
  E += diff;                                                                 \
  const float d5 = ldexpf(r1s, Es - E);                                      \
  const float g0 = r0 * pKv, g1 = r1 * pAv, g2 = r2 * pKv;                   \
  const float g3 = r3 * pBv, g4 = r4 * pKv, g5 = d5 * pNv;                   \
  const float n0 = g0 + g1;                                                  \
  const float n1 = __builtin_fmaf(skAp, g3, g1 + g2);                        \
  const float n2 = g2 + g3;                                                  \
  const float n3 = __builtin_fmaf(skBp, g5, g3 + g4);                        \
  const float n4 = g4 + g5;                                                  \
  r0 = n0; r1 = n1; r2 = n2; r3 = n3; r4 = n4;                               \
  if ((k_ & 3) == 3) {                                                       \
    const float m = fmaxf(fmaxf(fmaxf(r0, r1), fmaxf(r2, r3)), r4);          \
    const int sh2 = (m > 0.0f)                                               \
                      ? (187 - ((__float_as_int(m) >> 23) & 0xFF)) : 0;      \
    r0 = ldexpf(r0, sh2); r1 = ldexpf(r1, sh2); r2 = ldexpf(r2, sh2);        \
    r3 = ldexpf(r3, sh2); r4 = ldexpf(r4, sh2);                              \
    E -= sh2;                                                                \
  }                                                                          \
} while (0)

// One block (512 thr) per sample b.
//   group 0 (waves 0-3): R14's ALPHA block verbatim (t=0..1023).
//   group 1 (waves 4-7): R14's BETA block verbatim (rows 2047..1024).
//   Consumer waves are block-waves 0 and 4 -> both on SIMD 0 (i%4 mapping):
//   hardware dual-wave interleave fills each chain's dependency bubbles.
//   Rings live in 96 KB dynamic LDS (group-offset); per-wave code and
//   register pressure identical to R14 -> no codegen collapse.
__global__ __launch_bounds__(512, 2) void ctc_fused_kernel(
    const float* __restrict__ lp, const int* __restrict__ targets,
    const int* __restrict__ in_len, const int* __restrict__ tg_len,
    float* __restrict__ ws)
{
  extern __shared__ float dyn[];                   // 2 * 3*32*128 floats
  const int tid  = threadIdx.x;
  const int grp  = tid >> 8;                       // 0 = alpha, 1 = beta
  const int gtid = tid & 255;
  const int b = blockIdx.x;
  const size_t RSTR = (size_t)B_DIM * C_DIM;       // floats per t-row
  const int Tb = in_len[b];
  const float* base = lp + (size_t)b * C_DIM;

  float* ring = dyn + grp * (3 * 32 * C_DIM);      // group-private ring
  __shared__ float klred[2][3];

  float klacc = 0.f;                               // producers only

  if (grp == 0) {
    // ================= ALPHA group (R14 verbatim) =================
    const int TbA = (Tb < 1024) ? Tb : 1024;
    int tgA = 0, tgB = 0;
    float skA = 0.f, skB = 0.f;
    float r0 = 0.f, r1 = 0.f, r2 = 0.f, r3 = 0.f, r4 = 0.f;
    int E = SENT;
    float fA[4], fB[4], fK[4];

    if (gtid < 64) {
      const int l = gtid;
      tgA = targets[b * L_DIM + 2 * l];
      tgB = targets[b * L_DIM + 2 * l + 1];
      skA = (l > 0 && tgA != targets[b * L_DIM + 2 * l - 1]) ? 1.f : 0.f;
      skB = (tgB != tgA) ? 1.f : 0.f;
      if (l == 0) {
        r0 = __builtin_amdgcn_exp2f(base[0]   * LOG2E);
        r1 = __builtin_amdgcn_exp2f(base[tgA] * LOG2E);
        E = 0;
      }
    } else {
      const int ptid = gtid - 64;
      #pragma unroll
      for (int i = 0; i < 11; ++i) {
        const int task = i * 192 + ptid;
        if (task < 2048) {
          const int row = task >> 5;
          const int c4  = task & 31;
          const int t   = 1 + row;
          const float4 v = *(const float4*)(base + (size_t)t * RSTR + c4 * 4);
          float4 w;
          w.x = __builtin_amdgcn_exp2f(v.x * LOG2E);
          w.y = __builtin_amdgcn_exp2f(v.y * LOG2E);
          w.z = __builtin_amdgcn_exp2f(v.z * LOG2E);
          w.w = __builtin_amdgcn_exp2f(v.w * LOG2E);
          *(float4*)&ring[(row >> 5) * 32 * C_DIM + (row & 31) * C_DIM + c4 * 4] = w;
          if (t < Tb) {
            float s = v.x + v.y + v.z + v.w;
            if (c4 == 0) s -= v.x;
            klacc += s;
          }
        }
      }
      if (ptid < 32 && 0 < Tb) {
        const float4 v = *(const float4*)(base + ptid * 4);
        float s = v.x + v.y + v.z + v.w;
        if (ptid == 0) s -= v.x;
        klacc += s;
      }
    }
    __syncthreads();

    if (gtid < 64) {
      #pragma unroll
      for (int j = 0; j < 4; ++j) {
        fA[j] = ring[j * C_DIM + tgA]; fB[j] = ring[j * C_DIM + tgB];
        fK[j] = ring[j * C_DIM];
      }
    }
    float* pc = ring;
    float* pn = ring + 32 * C_DIM;
    float* pf = ring + 64 * C_DIM;

    for (int p = 0; p < NPH; ++p) {
      if (gtid < 64) {
        if (32 * p + 33 <= TbA) {
          #pragma unroll
          for (int k = 0; k < 32; ++k) { ALPHA_STEP(k); }
        } else {
          #pragma unroll
          for (int k = 0; k < 32; ++k) {
            const int t = 1 + 32 * p + k;
            if (t < TbA) { ALPHA_STEP(k); }
          }
        }
      } else {
        const int ptid = gtid - 64;
        const int t0 = 65 + 32 * p;
        if (t0 <= 1023) {
          #pragma unroll
          for (int i = 0; i < 6; ++i) {
            const int task = i * 192 + ptid;
            if (task < 1024) {
              const int row = task >> 5;
              const int c4  = task & 31;
              const int t   = t0 + row;
              if (t <= 1023) {
                const float4 v = *(const float4*)(base + (size_t)t * RSTR + c4 * 4);
                float4 w;
                w.x = __builtin_amdgcn_exp2f(v.x * LOG2E);
                w.y = __builtin_amdgcn_exp2f(v.y * LOG2E);
                w.z = __builtin_amdgcn_exp2f(v.z * LOG2E);
                w.w = __builtin_amdgcn_exp2f(v.w * LOG2E);
                *(float4*)&pf[row * C_DIM + c4 * 4] = w;
                if (t < Tb) {
                  float s = v.x + v.y + v.z + v.w;
                  if (c4 == 0) s -= v.x;
                  klacc += s;
                }
              }
            }
          }
        }
      }
      __syncthreads();
      float* tmp = pc; pc = pn; pn = pf; pf = tmp;
    }

    if (gtid < 64) {
      const int l = gtid;
      const float Ef = (float)E;
      float* dst = ws + AOFF + b * 257;
      dst[4 * l + 0] = __builtin_amdgcn_logf(r0) + Ef;
      dst[4 * l + 1] = __builtin_amdgcn_logf(r1) + Ef;
      dst[4 * l + 2] = __builtin_amdgcn_logf(r2) + Ef;
      dst[4 * l + 3] = __builtin_amdgcn_logf(r3) + Ef;
      if (l == 63) dst[256] = __builtin_amdgcn_logf(r4) + Ef;
    } else {
      float tot = klacc;
      tot += __shfl_xor(tot, 1, 64);  tot += __shfl_xor(tot, 2, 64);
      tot += __shfl_xor(tot, 4, 64);  tot += __shfl_xor(tot, 8, 64);
      tot += __shfl_xor(tot, 16, 64); tot += __shfl_xor(tot, 32, 64);
      if ((gtid & 63) == 0) klred[0][(gtid >> 6) - 1] = tot;
    }
    __syncthreads();
    if (gtid == 0) ws[KLA + b] = klred[0][0] + klred[0][1] + klred[0][2];

  } else {
    // ================= BETA group (R14 verbatim) =================
    int tgA = 0, tgB = 0, tgAn = 0;
    float skAp = 0.f, skBp = 0.f;
    float r0 = 0.f, r1 = 0.f, r2 = 0.f, r3 = 0.f, r4 = 0.f;
    int E = SENT;
    float fA[4], fB[4], fK[4], fN[4];

    if (gtid < 64) {
      const int l = gtid;
      tgA = targets[b * L_DIM + 2 * l];
      tgB = targets[b * L_DIM + 2 * l + 1];
      const int nidx = (l < 63) ? (2 * l + 2) : (2 * l);
      tgAn = targets[b * L_DIM + nidx];
      skAp = (tgB != tgA) ? 1.f : 0.f;
      skBp = (l < 63 && tgAn != tgB) ? 1.f : 0.f;
      const int Lt = tg_len[b];
      const int s0 = 4 * l;
      r0 = (s0 == 2 * Lt || s0 == 2 * Lt - 1) ? 1.f : 0.f;
      r1 = (s0 + 1 == 2 * Lt || s0 + 1 == 2 * Lt - 1) ? 1.f : 0.f;
      r2 = (s0 + 2 == 2 * Lt || s0 + 2 == 2 * Lt - 1) ? 1.f : 0.f;
      r3 = (s0 + 3 == 2 * Lt || s0 + 3 == 2 * Lt - 1) ? 1.f : 0.f;
      r4 = (s0 + 4 == 2 * Lt || s0 + 4 == 2 * Lt - 1) ? 1.f : 0.f;
      E = (r0 + r1 + r2 + r3 + r4 > 0.f) ? 0 : SENT;
    } else {
      const int ptid = gtid - 64;
      #pragma unroll
      for (int i = 0; i < 11; ++i) {
        const int task = i * 192 + ptid;
        if (task < 2048) {
          const int row = task >> 5;                // j = 0..63
          const int c4  = task & 31;
          const int t   = 2047 - row;
          const float4 v = *(const float4*)(base + (size_t)t * RSTR + c4 * 4);
          float4 w;
          w.x = __builtin_amdgcn_exp2f(v.x * LOG2E);
          w.y = __builtin_amdgcn_exp2f(v.y * LOG2E);
          w.z = __builtin_amdgcn_exp2f(v.z * LOG2E);
          w.w = __builtin_amdgcn_exp2f(v.w * LOG2E);
          *(float4*)&ring[(row >> 5) * 32 * C_DIM + (row & 31) * C_DIM + c4 * 4] = w;
          if (t < Tb) {
            float s = v.x + v.y + v.z + v.w;
            if (c4 == 0) s -= v.x;
            klacc += s;
          }
        }
      }
    }
    __syncthreads();

    if (gtid < 64) {
      #pragma unroll
      for (int j = 0; j < 4; ++j) {
        fA[j] = ring[j * C_DIM + tgA]; fB[j] = ring[j * C_DIM + tgB];
        fK[j] = ring[j * C_DIM];       fN[j] = ring[j * C_DIM + tgAn];
      }
    }
    float* pc = ring;
    float* pn = ring + 32 * C_DIM;
    float* pf = ring + 64 * C_DIM;

    for (int p = 0; p < NPH; ++p) {
      if (gtid < 64) {
        const int rmax = 2047 - 32 * p;
        const int rmin = rmax - 31;
        if (rmax < Tb) {
          #pragma unroll
          for (int k = 0; k < 32; ++k) { BETA_STEP(k); }
        } else if (rmin < Tb) {
          #pragma unroll
          for (int k = 0; k < 32; ++k) {
            const int r = 2047 - 32 * p - k;
            if (r < Tb) { BETA_STEP(k); }
          }
        }
      } else {
        const int ptid = gtid - 64;
        const int t0 = 1983 - 32 * p;
        if (t0 >= 1024) {
          #pragma unroll
          for (int i = 0; i < 6; ++i) {
            const int task = i * 192 + ptid;
            if (task < 1024) {
              const int row = task >> 5;
              const int c4  = task & 31;
              const int t   = t0 - row;
              if (t >= 1024) {
                const float4 v = *(const float4*)(base + (size_t)t * RSTR + c4 * 4);
                float4 w;
                w.x = __builtin_amdgcn_exp2f(v.x * LOG2E);
                w.y = __builtin_amdgcn_exp2f(v.y * LOG2E);
                w.z = __builtin_amdgcn_exp2f(v.z * LOG2E);
                w.w = __builtin_amdgcn_exp2f(v.w * LOG2E);
                *(float4*)&pf[row * C_DIM + c4 * 4] = w;
                if (t < Tb) {
                  float s = v.x + v.y + v.z + v.w;
                  if (c4 == 0) s -= v.x;
                  klacc += s;
                }
              }
            }
          }
        }
      }
      __syncthreads();
      float* tmp = pc; pc = pn; pn = pf; pf = tmp;
    }

    if (gtid < 64) {
      const int l = gtid;
      const float Ef = (float)E;
      float* dst = ws + BOFF + b * 257;
      dst[4 * l + 0] = __builtin_amdgcn_logf(r0) + Ef;
      dst[4 * l + 1] = __builtin_amdgcn_logf(r1) + Ef;
      dst[4 * l + 2] = __builtin_amdgcn_logf(r2) + Ef;
      dst[4 * l + 3] = __builtin_amdgcn_logf(r3) + Ef;
      if (l == 63) dst[256] = __builtin_amdgcn_logf(r4) + Ef;
    } else {
      float tot = klacc;
      tot += __shfl_xor(tot, 1, 64);  tot += __shfl_xor(tot, 2, 64);
      tot += __shfl_xor(tot, 4, 64);  tot += __shfl_xor(tot, 8, 64);
      tot += __shfl_xor(tot, 16, 64); tot += __shfl_xor(tot, 32, 64);
      if ((gtid & 63) == 0) klred[1][(gtid >> 6) - 1] = tot;
    }
    __syncthreads();
    if (gtid == 0) ws[KLB + b] = klred[1][0] + klred[1][1] + klred[1][2];
  }
}

// Per-sample combine: ll = logsumexp_s(alpha_log2[s] + beta_log2[s]); loss.
__global__ __launch_bounds__(64) void ctc_combine_kernel(
    const float* __restrict__ ws_in, const int* __restrict__ in_len,
    float* __restrict__ ws_out)
{
  const int b = blockIdx.x;
  const int l = threadIdx.x;
  const float* a  = ws_in + AOFF + b * 257;
  const float* bb = ws_in + BOFF + b * 257;
  float x0 = a[4 * l + 0] + bb[4 * l + 0];
  float x1 = a[4 * l + 1] + bb[4 * l + 1];
  float x2 = a[4 * l + 2] + bb[4 * l + 2];
  float x3 = a[4 * l + 3] + bb[4 * l + 3];
  float x4 = (l == 63) ? (a[256] + bb[256]) : -3.0e38f;
  float m = fmaxf(fmaxf(fmaxf(x0, x1), fmaxf(x2, x3)), x4);
  m = fmaxf(m, __shfl_xor(m, 1, 64));  m = fmaxf(m, __shfl_xor(m, 2, 64));
  m = fmaxf(m, __shfl_xor(m, 4, 64));  m = fmaxf(m, __shfl_xor(m, 8, 64));
  m = fmaxf(m, __shfl_xor(m, 16, 64)); m = fmaxf(m, __shfl_xor(m, 32, 64));
  const float ms = fmaxf(m, -1.0e37f);
  float s = __builtin_amdgcn_exp2f(x0 - ms) + __builtin_amdgcn_exp2f(x1 - ms)
          + __builtin_amdgcn_exp2f(x2 - ms) + __builtin_amdgcn_exp2f(x3 - ms)
          + __builtin_amdgcn_exp2f(x4 - ms);
  s += __shfl_xor(s, 1, 64);  s += __shfl_xor(s, 2, 64);
  s += __shfl_xor(s, 4, 64);  s += __shfl_xor(s, 8, 64);
  s += __shfl_xor(s, 16, 64); s += __shfl_xor(s, 32, 64);
  if (l == 0) {
    float ctc = 0.f;
    if (s > 0.f && m > -1.0e30f) {
      ctc = -((ms + __builtin_amdgcn_logf(s)) * LN2);
    }
    const int Tb = in_len[b];
    const float u    = 1.0f / (C_DIM - 1);
    const float logu = -4.8441870864585910f;       // log(1/127)
    const float kls  = ws_in[KLA + b] + ws_in[KLB + b];
    const float klmean = logu - u * kls / (float)Tb;
    ws_out[LOSS + b] = (1.0f - SMOOTH) * ctc + SMOOTH * klmean;
  }
}

__global__ __launch_bounds__(128) void ctc_mean_kernel(
    const float* __restrict__ ws, float* __restrict__ out)
{
  __shared__ float red[128];
  const int tid = threadIdx.x;
  red[tid] = (tid < B_DIM) ? ws[LOSS + tid] : 0.f;
  __syncthreads();
  for (int off = 64; off > 0; off >>= 1) {
    if (tid < off) red[tid] += red[tid + off];
    __syncthreads();
  }
  if (tid == 0) out[0] = red[0] / (float)B_DIM;
}

extern "C" void kernel_launch(void* const* d_in, const int* in_sizes, int n_in,
                              void* d_out, int out_size, void* d_ws, size_t ws_size,
                              hipStream_t stream) {
  const float* lp      = (const float*)d_in[0];
  const int* targets   = (const int*)d_in[1];
  const int* in_len    = (const int*)d_in[2];
  const int* tg_len    = (const int*)d_in[3];
  float* ws  = (float*)d_ws;
  float* out = (float*)d_out;

  const size_t dynBytes = 2u * 3u * 32u * C_DIM * sizeof(float);  // 98304 B
  static bool attrSet = false;   // host-side idempotent config, capture-safe
  if (!attrSet) {
    (void)hipFuncSetAttribute((const void*)ctc_fused_kernel,
                              hipFuncAttributeMaxDynamicSharedMemorySize,
                              (int)dynBytes);
    attrSet = true;
  }

  hipLaunchKernelGGL(ctc_fused_kernel, dim3(B_DIM), dim3(512), dynBytes, stream,
                     lp, targets, in_len, tg_len, ws);
  hipLaunchKernelGGL(ctc_combine_kernel, dim3(B_DIM), dim3(64), 0, stream,
                     ws, in_len, ws);
  hipLaunchKernelGGL(ctc_mean_kernel, dim3(1), dim3(128), 0, stream,
                     ws, out);
}

// Round 18
// 84.435 us; speedup vs baseline: 1.9215x; 1.6566x over previous
//
#include <hip/hip_runtime.h>
#include <math.h>

#define T_DIM 2048
#define B_DIM 96
#define C_DIM 128
#define L_DIM 128
#define LOG2E 1.4426950408889634f
#define LN2 0.69314718055994531f
#define SMOOTH 0.1f
#define SENT (-(1 << 30))       // virgin lane frame (f32-exact power of 2)
#define SENTF (-1073741824.0f)
#define NPH 32                  // 32 phases x 32 steps per chain

// ws layout (floats)
#define AOFF 0                  // 96*257 alpha log2 values at t=1023
#define BOFF 24672              // 96*257 beta  log2 values at t=1023
#define KLA  49344              // 96 partial KL (rows 0..1023)
#define KLB  49440              // 96 partial KL (rows 1024..2047)
#define LOSS 49536              // 96 per-sample losses

__device__ __forceinline__ float dpp_shr1_f(float x) {
  return __int_as_float(__builtin_amdgcn_update_dpp(
      0, __float_as_int(x), 0x138 /*WAVE_SR1*/, 0xF, 0xF, true));
}
__device__ __forceinline__ float dpp_shl1_f(float x) {
  return __int_as_float(__builtin_amdgcn_update_dpp(
      0, __float_as_int(x), 0x130 /*WAVE_SL1*/, 0xF, 0xF, true));
}

// Window exchange (once per 4 steps): recenter to 2^50, swap frames,
// virgin pre-adoption, branchless adoption, scale = 2^(Es-E) (exact pow2).
#define AEXCH() do {                                                         \
  const float m = fmaxf(fmaxf(fmaxf(r0, r1), fmaxf(r2, r3)), r4);            \
  const int sh2 = (m > 0.0f) ? (177 - ((__float_as_int(m) >> 23) & 0xFF)) : 0;\
  r0 = ldexpf(r0, sh2); r1 = ldexpf(r1, sh2); r2 = ldexpf(r2, sh2);          \
  r3 = ldexpf(r3, sh2); r4 = ldexpf(r4, sh2);                                \
  E -= sh2;                                                                  \
  float Esf = dpp_shr1_f((float)E);                                          \
  Esf = (tid == 0) ? SENTF : Esf;                                            \
  const int Es = (int)Esf;                                                   \
  const bool live = (Es != SENT);                                            \
  if (E == SENT && live) E = Es;                                             \
  int sh = (Es - E) - 60; sh = (sh > 0) ? sh : 0; sh = (sh > 252) ? 252 : sh;\
  r0 = ldexpf(r0, -sh); r1 = ldexpf(r1, -sh); r2 = ldexpf(r2, -sh);          \
  r3 = ldexpf(r3, -sh); r4 = ldexpf(r4, -sh);                                \
  E += sh;                                                                   \
  const int diff = Es - E;                                                   \
  int dc = (diff < -126) ? -126 : diff;                                      \
  float sc = __int_as_float((127 + dc) << 23);                               \
  sc = (diff < -126) ? 0.0f : sc;                                            \
  scale = live ? sc : 0.0f;                                                  \
} while (0)

#define BEXCH() do {                                                         \
  const float m = fmaxf(fmaxf(fmaxf(r0, r1), fmaxf(r2, r3)), r4);            \
  const int sh2 = (m > 0.0f) ? (177 - ((__float_as_int(m) >> 23) & 0xFF)) : 0;\
  r0 = ldexpf(r0, sh2); r1 = ldexpf(r1, sh2); r2 = ldexpf(r2, sh2);          \
  r3 = ldexpf(r3, sh2); r4 = ldexpf(r4, sh2);                                \
  E -= sh2;                                                                  \
  float Esf = dpp_shl1_f((float)E);                                          \
  Esf = (tid == 63) ? SENTF : Esf;                                           \
  const int Es = (int)Esf;                                                   \
  const bool live = (Es != SENT);                                            \
  if (E == SENT && live) E = Es;                                             \
  int sh = (Es - E) - 60; sh = (sh > 0) ? sh : 0; sh = (sh > 252) ? 252 : sh;\
  r0 = ldexpf(r0, -sh); r1 = ldexpf(r1, -sh); r2 = ldexpf(r2, -sh);          \
  r3 = ldexpf(r3, -sh); r4 = ldexpf(r4, -sh);                                \
  E += sh;                                                                   \
  const int diff = Es - E;                                                   \
  int dc = (diff < -126) ? -126 : diff;                                      \
  float sc = __int_as_float((127 + dc) << 23);                               \
  sc = (diff < -126) ? 0.0f : sc;                                            \
  scale = live ? sc : 0.0f;                                                  \
} while (0)

// ALPHA step: crossing is ONE dpp + ONE exact pow2 multiply.
#define ALPHA_STEP(kk_) do {                                                 \
  const int k_ = (kk_);                                                      \
  const float pAv = fA[k_ & 3], pBv = fB[k_ & 3], pKv = fK[k_ & 3];          \
  {                                                                          \
    const int kn = k_ + 4;                                                   \
    const float* nr = (kn < 32) ? (pc + kn * C_DIM)                          \
                                : (pn + (kn - 32) * C_DIM);                  \
    fA[k_ & 3] = nr[tgA]; fB[k_ & 3] = nr[tgB]; fK[k_ & 3] = nr[0];          \
  }                                                                          \
  const float r3s = dpp_shr1_f(r3);                                          \
  const float d3  = r3s * scale;                                             \
  const float n0 = (r0 + d3) * pKv;                                          \
  const float n1 = __builtin_fmaf(skA, d3, r0 + r1) * pAv;                   \
  const float n2 = (r2 + r1) * pKv;                                          \
  const float n3 = __builtin_fmaf(skB, r1, r3 + r2) * pBv;                   \
  const float n4 = (r4 + r3) * pKv;                                          \
  r0 = n0; r1 = n1; r2 = n2; r3 = n3; r4 = n4;                               \
  if ((k_ & 3) == 3) { AEXCH(); }                                            \
} while (0)

// BETA step: mirror.
#define BETA_STEP(kk_) do {                                                  \
  const int k_ = (kk_);                                                      \
  const float pAv = fA[k_ & 3], pBv = fB[k_ & 3], pKv = fK[k_ & 3];          \
  const float pNv = fN[k_ & 3];                                              \
  {                                                                          \
    const int kn = k_ + 4;                                                   \
    const float* nr = (kn < 32) ? (pc + kn * C_DIM)                          \
                                : (pn + (kn - 32) * C_DIM);                  \
    fA[k_ & 3] = nr[tgA]; fB[k_ & 3] = nr[tgB]; fK[k_ & 3] = nr[0];          \
    fN[k_ & 3] = nr[tgAn];                                                   \
  }                                                                          \
  const float r1s = dpp_shl1_f(r1);                                          \
  const float d5  = r1s * scale;                                             \
  const float g0 = r0 * pKv, g1 = r1 * pAv, g2 = r2 * pKv;                   \
  const float g3 = r3 * pBv, g4 = r4 * pKv, g5 = d5 * pNv;                   \
  const float n0 = g0 + g1;                                                  \
  const float n1 = __builtin_fmaf(skAp, g3, g1 + g2);                        \
  const float n2 = g2 + g3;                                                  \
  const float n3 = __builtin_fmaf(skBp, g5, g3 + g4);                        \
  const float n4 = g4 + g5;                                                  \
  r0 = n0; r1 = n1; r2 = n2; r3 = n3; r4 = n4;                               \
  if ((k_ & 3) == 3) { BEXCH(); }                                            \
} while (0)

// Blocks 0..95: ALPHA half (t=0..1023). Blocks 96..191: BETA half (rows
// 2047..1024). R14 structure byte-identical outside the step math.
__global__ __launch_bounds__(256) void ctc_fused_kernel(
    const float* __restrict__ lp, const int* __restrict__ targets,
    const int* __restrict__ in_len, const int* __restrict__ tg_len,
    float* __restrict__ ws)
{
  const int tid = threadIdx.x;
  const int bid = blockIdx.x;
  const int isBeta = (bid >= B_DIM);
  const int b = isBeta ? bid - B_DIM : bid;
  const size_t RSTR = (size_t)B_DIM * C_DIM;       // floats per t-row
  const int Tb = in_len[b];
  const float* base = lp + (size_t)b * C_DIM;

  __shared__ float rows[3][32][C_DIM];             // 48 KB ring of PROBS
  __shared__ float klred[3];

  float klacc = 0.f;                               // producers only

  if (!isBeta) {
    // ================= ALPHA half =================
    const int TbA = (Tb < 1024) ? Tb : 1024;
    int tgA = 0, tgB = 0;
    float skA = 0.f, skB = 0.f;
    float r0 = 0.f, r1 = 0.f, r2 = 0.f, r3 = 0.f, r4 = 0.f;
    int E = SENT;
    float scale = 0.f;
    float fA[4], fB[4], fK[4];

    if (tid < 64) {
      const int l = tid;
      tgA = targets[b * L_DIM + 2 * l];
      tgB = targets[b * L_DIM + 2 * l + 1];
      skA = (l > 0 && tgA != targets[b * L_DIM + 2 * l - 1]) ? 1.f : 0.f;
      skB = (tgB != tgA) ? 1.f : 0.f;
      if (l == 0) {
        r0 = __builtin_amdgcn_exp2f(base[0]   * LOG2E);
        r1 = __builtin_amdgcn_exp2f(base[tgA] * LOG2E);
        E = 0;
      }
    } else {
      const int ptid = tid - 64;
      #pragma unroll
      for (int i = 0; i < 11; ++i) {
        const int task = i * 192 + ptid;
        if (task < 2048) {
          const int row = task >> 5;
          const int c4  = task & 31;
          const int t   = 1 + row;
          const float4 v = *(const float4*)(base + (size_t)t * RSTR + c4 * 4);
          float4 w;
          w.x = __builtin_amdgcn_exp2f(v.x * LOG2E);
          w.y = __builtin_amdgcn_exp2f(v.y * LOG2E);
          w.z = __builtin_amdgcn_exp2f(v.z * LOG2E);
          w.w = __builtin_amdgcn_exp2f(v.w * LOG2E);
          *(float4*)&rows[row >> 5][row & 31][c4 * 4] = w;
          if (t < Tb) {
            float s = v.x + v.y + v.z + v.w;
            if (c4 == 0) s -= v.x;
            klacc += s;
          }
        }
      }
      if (ptid < 32 && 0 < Tb) {
        const float4 v = *(const float4*)(base + ptid * 4);
        float s = v.x + v.y + v.z + v.w;
        if (ptid == 0) s -= v.x;
        klacc += s;
      }
    }
    __syncthreads();

    if (tid < 64) {
      #pragma unroll
      for (int j = 0; j < 4; ++j) {
        fA[j] = rows[0][j][tgA]; fB[j] = rows[0][j][tgB]; fK[j] = rows[0][j][0];
      }
      AEXCH();                                     // initial frame exchange
    }
    float* pc = &rows[0][0][0];
    float* pn = &rows[1][0][0];
    float* pf = &rows[2][0][0];

    for (int p = 0; p < NPH; ++p) {
      if (tid < 64) {
        if (32 * p + 33 <= TbA) {
          #pragma unroll
          for (int k = 0; k < 32; ++k) { ALPHA_STEP(k); }
        } else {
          #pragma unroll
          for (int k = 0; k < 32; ++k) {
            const int t = 1 + 32 * p + k;
            if (t < TbA) { ALPHA_STEP(k); }
          }
        }
      } else {
        const int ptid = tid - 64;
        const int t0 = 65 + 32 * p;
        if (t0 <= 1023) {
          #pragma unroll
          for (int i = 0; i < 6; ++i) {
            const int task = i * 192 + ptid;
            if (task < 1024) {
              const int row = task >> 5;
              const int c4  = task & 31;
              const int t   = t0 + row;
              if (t <= 1023) {
                const float4 v = *(const float4*)(base + (size_t)t * RSTR + c4 * 4);
                float4 w;
                w.x = __builtin_amdgcn_exp2f(v.x * LOG2E);
                w.y = __builtin_amdgcn_exp2f(v.y * LOG2E);
                w.z = __builtin_amdgcn_exp2f(v.z * LOG2E);
                w.w = __builtin_amdgcn_exp2f(v.w * LOG2E);
                *(float4*)&pf[row * C_DIM + c4 * 4] = w;
                if (t < Tb) {
                  float s = v.x + v.y + v.z + v.w;
                  if (c4 == 0) s -= v.x;
                  klacc += s;
                }
              }
            }
          }
        }
      }
      __syncthreads();
      float* tmp = pc; pc = pn; pn = pf; pf = tmp;
    }

    if (tid < 64) {
      const int l = tid;
      const float Ef = (float)E;
      float* dst = ws + AOFF + b * 257;
      dst[4 * l + 0] = __builtin_amdgcn_logf(r0) + Ef;
      dst[4 * l + 1] = __builtin_amdgcn_logf(r1) + Ef;
      dst[4 * l + 2] = __builtin_amdgcn_logf(r2) + Ef;
      dst[4 * l + 3] = __builtin_amdgcn_logf(r3) + Ef;
      if (l == 63) dst[256] = __builtin_amdgcn_logf(r4) + Ef;
    } else {
      float tot = klacc;
      tot += __shfl_xor(tot, 1, 64);  tot += __shfl_xor(tot, 2, 64);
      tot += __shfl_xor(tot, 4, 64);  tot += __shfl_xor(tot, 8, 64);
      tot += __shfl_xor(tot, 16, 64); tot += __shfl_xor(tot, 32, 64);
      if ((tid & 63) == 0) klred[(tid >> 6) - 1] = tot;
    }
    __syncthreads();
    if (tid == 0) ws[KLA + b] = klred[0] + klred[1] + klred[2];

  } else {
    // ================= BETA half =================
    int tgA = 0, tgB = 0, tgAn = 0;
    float skAp = 0.f, skBp = 0.f;
    float r0 = 0.f, r1 = 0.f, r2 = 0.f, r3 = 0.f, r4 = 0.f;
    int E = SENT;
    float scale = 0.f;
    float fA[4], fB[4], fK[4], fN[4];

    if (tid < 64) {
      const int l = tid;
      tgA = targets[b * L_DIM + 2 * l];
      tgB = targets[b * L_DIM + 2 * l + 1];
      const int nidx = (l < 63) ? (2 * l + 2) : (2 * l);
      tgAn = targets[b * L_DIM + nidx];
      skAp = (tgB != tgA) ? 1.f : 0.f;
      skBp = (l < 63 && tgAn != tgB) ? 1.f : 0.f;
      const int Lt = tg_len[b];
      const int s0 = 4 * l;
      r0 = (s0 == 2 * Lt || s0 == 2 * Lt - 1) ? 1.f : 0.f;
      r1 = (s0 + 1 == 2 * Lt || s0 + 1 == 2 * Lt - 1) ? 1.f : 0.f;
      r2 = (s0 + 2 == 2 * Lt || s0 + 2 == 2 * Lt - 1) ? 1.f : 0.f;
      r3 = (s0 + 3 == 2 * Lt || s0 + 3 == 2 * Lt - 1) ? 1.f : 0.f;
      r4 = (s0 + 4 == 2 * Lt || s0 + 4 == 2 * Lt - 1) ? 1.f : 0.f;
      E = (r0 + r1 + r2 + r3 + r4 > 0.f) ? 0 : SENT;
    } else {
      const int ptid = tid - 64;
      #pragma unroll
      for (int i = 0; i < 11; ++i) {
        const int task = i * 192 + ptid;
        if (task < 2048) {
          const int row = task >> 5;                // j = 0..63
          const int c4  = task & 31;
          const int t   = 2047 - row;
          const float4 v = *(const float4*)(base + (size_t)t * RSTR + c4 * 4);
          float4 w;
          w.x = __builtin_amdgcn_exp2f(v.x * LOG2E);
          w.y = __builtin_amdgcn_exp2f(v.y * LOG2E);
          w.z = __builtin_amdgcn_exp2f(v.z * LOG2E);
          w.w = __builtin_amdgcn_exp2f(v.w * LOG2E);
          *(float4*)&rows[row >> 5][row & 31][c4 * 4] = w;
          if (t < Tb) {
            float s = v.x + v.y + v.z + v.w;
            if (c4 == 0) s -= v.x;
            klacc += s;
          }
        }
      }
    }
    __syncthreads();

    if (tid < 64) {
      #pragma unroll
      for (int j = 0; j < 4; ++j) {
        fA[j] = rows[0][j][tgA]; fB[j] = rows[0][j][tgB];
        fK[j] = rows[0][j][0];   fN[j] = rows[0][j][tgAn];
      }
      BEXCH();                                     // initial frame exchange
    }
    float* pc = &rows[0][0][0];
    float* pn = &rows[1][0][0];
    float* pf = &rows[2][0][0];

    for (int p = 0; p < NPH; ++p) {
      if (tid < 64) {
        const int rmax = 2047 - 32 * p;
        const int rmin = rmax - 31;
        if (rmax < Tb) {
          #pragma unroll
          for (int k = 0; k < 32; ++k) { BETA_STEP(k); }
        } else if (rmin < Tb) {
          #pragma unroll
          for (int k = 0; k < 32; ++k) {
            const int r = 2047 - 32 * p - k;
            if (r < Tb) { BETA_STEP(k); }
          }
        }
      } else {
        const int ptid = tid - 64;
        const int t0 = 1983 - 32 * p;
        if (t0 >= 1024) {
          #pragma unroll
          for (int i = 0; i < 6; ++i) {
            const int task = i * 192 + ptid;
            if (task < 1024) {
              const int row = task >> 5;
              const int c4  = task & 31;
              const int t   = t0 - row;
              if (t >= 1024) {
                const float4 v = *(const float4*)(base + (size_t)t * RSTR + c4 * 4);
                float4 w;
                w.x = __builtin_amdgcn_exp2f(v.x * LOG2E);
                w.y = __builtin_amdgcn_exp2f(v.y * LOG2E);
                w.z = __builtin_amdgcn_exp2f(v.z * LOG2E);
                w.w = __builtin_amdgcn_exp2f(v.w * LOG2E);
                *(float4*)&pf[row * C_DIM + c4 * 4] = w;
                if (t < Tb) {
                  float s = v.x + v.y + v.z + v.w;
                  if (c4 == 0) s -= v.x;
                  klacc += s;
                }
              }
            }
          }
        }
      }
      __syncthreads();
      float* tmp = pc; pc = pn; pn = pf; pf = tmp;
    }

    if (tid < 64) {
      const int l = tid;
      const float Ef = (float)E;
      float* dst = ws + BOFF + b * 257;
      dst[4 * l + 0] = __builtin_amdgcn_logf(r0) + Ef;
      dst[4 * l + 1] = __builtin_amdgcn_logf(r1) + Ef;
      dst[4 * l + 2] = __builtin_amdgcn_logf(r2) + Ef;
      dst[4 * l + 3] = __builtin_amdgcn_logf(r3) + Ef;
      if (l == 63) dst[256] = __builtin_amdgcn_logf(r4) + Ef;
    } else {
      float tot = klacc;
      tot += __shfl_xor(tot, 1, 64);  tot += __shfl_xor(tot, 2, 64);
      tot += __shfl_xor(tot, 4, 64);  tot += __shfl_xor(tot, 8, 64);
      tot += __shfl_xor(tot, 16, 64); tot += __shfl_xor(tot, 32, 64);
      if ((tid & 63) == 0) klred[(tid >> 6) - 1] = tot;
    }
    __syncthreads();
    if (tid == 0) ws[KLB + b] = klred[0] + klred[1] + klred[2];
  }
}

// Per-sample combine: ll = logsumexp_s(alpha_log2[s] + beta_log2[s]); loss.
__global__ __launch_bounds__(64) void ctc_combine_kernel(
    const float* __restrict__ ws_in, const int* __restrict__ in_len,
    float* __restrict__ ws_out)
{
  const int b = blockIdx.x;
  const int l = threadIdx.x;
  const float* a  = ws_in + AOFF + b * 257;
  const float* bb = ws_in + BOFF + b * 257;
  float x0 = a[4 * l + 0] + bb[4 * l + 0];
  float x1 = a[4 * l + 1] + bb[4 * l + 1];
  float x2 = a[4 * l + 2] + bb[4 * l + 2];
  float x3 = a[4 * l + 3] + bb[4 * l + 3];
  float x4 = (l == 63) ? (a[256] + bb[256]) : -3.0e38f;
  float m = fmaxf(fmaxf(fmaxf(x0, x1), fmaxf(x2, x3)), x4);
  m = fmaxf(m, __shfl_xor(m, 1, 64));  m = fmaxf(m, __shfl_xor(m, 2, 64));
  m = fmaxf(m, __shfl_xor(m, 4, 64));  m = fmaxf(m, __shfl_xor(m, 8, 64));
  m = fmaxf(m, __shfl_xor(m, 16, 64)); m = fmaxf(m, __shfl_xor(m, 32, 64));
  const float ms = fmaxf(m, -1.0e37f);
  float s = __builtin_amdgcn_exp2f(x0 - ms) + __builtin_amdgcn_exp2f(x1 - ms)
          + __builtin_amdgcn_exp2f(x2 - ms) + __builtin_amdgcn_exp2f(x3 - ms)
          + __builtin_amdgcn_exp2f(x4 - ms);
  s += __shfl_xor(s, 1, 64);  s += __shfl_xor(s, 2, 64);
  s += __shfl_xor(s, 4, 64);  s += __shfl_xor(s, 8, 64);
  s += __shfl_xor(s, 16, 64); s += __shfl_xor(s, 32, 64);
  if (l == 0) {
    float ctc = 0.f;
    if (s > 0.f && m > -1.0e30f) {
      ctc = -((ms + __builtin_amdgcn_logf(s)) * LN2);
    }
    const int Tb = in_len[b];
    const float u    = 1.0f / (C_DIM - 1);
    const float logu = -4.8441870864585910f;       // log(1/127)
    const float kls  = ws_in[KLA + b] + ws_in[KLB + b];
    const float klmean = logu - u * kls / (float)Tb;
    ws_out[LOSS + b] = (1.0f - SMOOTH) * ctc + SMOOTH * klmean;
  }
}

__global__ __launch_bounds__(128) void ctc_mean_kernel(
    const float* __restrict__ ws, float* __restrict__ out)
{
  __shared__ float red[128];
  const int tid = threadIdx.x;
  red[tid] = (tid < B_DIM) ? ws[LOSS + tid] : 0.f;
  __syncthreads();
  for (int off = 64; off > 0; off >>= 1) {
    if (tid < off) red[tid] += red[tid + off];
    __syncthreads();
  }
  if (tid == 0) out[0] = red[0] / (float)B_DIM;
}

extern "C" void kernel_launch(void* const* d_in, const int* in_sizes, int n_in,
                              void* d_out, int out_size, void* d_ws, size_t ws_size,
                              hipStream_t stream) {
  const float* lp      = (const float*)d_in[0];
  const int* targets   = (const int*)d_in[1];
  const int* in_len    = (const int*)d_in[2];
  const int* tg_len    = (const int*)d_in[3];
  float* ws  = (float*)d_ws;
  float* out = (float*)d_out;

  hipLaunchKernelGGL(ctc_fused_kernel, dim3(2 * B_DIM), dim3(256), 0, stream,
                     lp, targets, in_len, tg_len, ws);
  hipLaunchKernelGGL(ctc_combine_kernel, dim3(B_DIM), dim3(64), 0, stream,
                     ws, in_len, ws);
  hipLaunchKernelGGL(ctc_mean_kernel, dim3(1), dim3(128), 0, stream,
                     ws, out);
}

// Round 19
// 81.445 us; speedup vs baseline: 1.9921x; 1.0367x over previous
//
#include <hip/hip_runtime.h>
#include <math.h>

#define T_DIM 2048
#define B_DIM 96
#define C_DIM 128
#define L_DIM 128
#define LOG2E 1.4426950408889634f
#define LN2 0.69314718055994531f
#define SMOOTH 0.1f
#define SENT (-(1 << 30))       // virgin lane frame (f32-exact power of 2)
#define SENTF (-1073741824.0f)
#define NPH 32                  // 32 phases x 32 steps per chain

// ws layout (floats)
#define AOFF 0
#define BOFF 24672
#define KLA  49344
#define KLB  49440
#define LOSS 49536

__device__ __forceinline__ float dpp_shr1_f(float x) {
  return __int_as_float(__builtin_amdgcn_update_dpp(
      0, __float_as_int(x), 0x138 /*WAVE_SR1*/, 0xF, 0xF, true));
}
__device__ __forceinline__ float dpp_shl1_f(float x) {
  return __int_as_float(__builtin_amdgcn_update_dpp(
      0, __float_as_int(x), 0x130 /*WAVE_SL1*/, 0xF, 0xF, true));
}

// Window exchange (R18-proven): recenter to 2^50, swap frames, virgin
// pre-adoption, scale = 2^(Es-E) exact pow2.
#define AEXCH() do {                                                         \
  const float m = fmaxf(fmaxf(fmaxf(r0, r1), fmaxf(r2, r3)), r4);            \
  const int sh2 = (m > 0.0f) ? (177 - ((__float_as_int(m) >> 23) & 0xFF)) : 0;\
  r0 = ldexpf(r0, sh2); r1 = ldexpf(r1, sh2); r2 = ldexpf(r2, sh2);          \
  r3 = ldexpf(r3, sh2); r4 = ldexpf(r4, sh2);                                \
  E -= sh2;                                                                  \
  float Esf = dpp_shr1_f((float)E);                                          \
  Esf = (tid == 0) ? SENTF : Esf;                                            \
  const int Es = (int)Esf;                                                   \
  const bool live = (Es != SENT);                                            \
  if (E == SENT && live) E = Es;                                             \
  int sh = (Es - E) - 60; sh = (sh > 0) ? sh : 0; sh = (sh > 252) ? 252 : sh;\
  r0 = ldexpf(r0, -sh); r1 = ldexpf(r1, -sh); r2 = ldexpf(r2, -sh);          \
  r3 = ldexpf(r3, -sh); r4 = ldexpf(r4, -sh);                                \
  E += sh;                                                                   \
  const int diff = Es - E;                                                   \
  int dc = (diff < -126) ? -126 : diff;                                      \
  float sc = __int_as_float((127 + dc) << 23);                               \
  sc = (diff < -126) ? 0.0f : sc;                                            \
  scale = live ? sc : 0.0f;                                                  \
} while (0)

#define BEXCH() do {                                                         \
  const float m = fmaxf(fmaxf(fmaxf(r0, r1), fmaxf(r2, r3)), r4);            \
  const int sh2 = (m > 0.0f) ? (177 - ((__float_as_int(m) >> 23) & 0xFF)) : 0;\
  r0 = ldexpf(r0, sh2); r1 = ldexpf(r1, sh2); r2 = ldexpf(r2, sh2);          \
  r3 = ldexpf(r3, sh2); r4 = ldexpf(r4, sh2);                                \
  E -= sh2;                                                                  \
  float Esf = dpp_shl1_f((float)E);                                          \
  Esf = (tid == 63) ? SENTF : Esf;                                           \
  const int Es = (int)Esf;                                                   \
  const bool live = (Es != SENT);                                            \
  if (E == SENT && live) E = Es;                                             \
  int sh = (Es - E) - 60; sh = (sh > 0) ? sh : 0; sh = (sh > 252) ? 252 : sh;\
  r0 = ldexpf(r0, -sh); r1 = ldexpf(r1, -sh); r2 = ldexpf(r2, -sh);          \
  r3 = ldexpf(r3, -sh); r4 = ldexpf(r4, -sh);                                \
  E += sh;                                                                   \
  const int diff = Es - E;                                                   \
  int dc = (diff < -126) ? -126 : diff;                                      \
  float sc = __int_as_float((127 + dc) << 23);                               \
  sc = (diff < -126) ? 0.0f : sc;                                            \
  scale = live ? sc : 0.0f;                                                  \
} while (0)

// Math-only steps (NO LDS ops) — R18-proven recurrence.
#define AMATH(par_, j_) do {                                                 \
  const float pAv = sA[par_][j_], pBv = sB[par_][j_], pKv = sK[par_][j_];    \
  const float r3s = dpp_shr1_f(r3);                                          \
  const float d3  = r3s * scale;                                             \
  const float n0 = (r0 + d3) * pKv;                                          \
  const float n1 = __builtin_fmaf(skA, d3, r0 + r1) * pAv;                   \
  const float n2 = (r2 + r1) * pKv;                                          \
  const float n3 = __builtin_fmaf(skB, r1, r3 + r2) * pBv;                   \
  const float n4 = (r4 + r3) * pKv;                                          \
  r0 = n0; r1 = n1; r2 = n2; r3 = n3; r4 = n4;                               \
} while (0)

#define BMATH(par_, j_) do {                                                 \
  const float pAv = sA[par_][j_], pBv = sB[par_][j_], pKv = sK[par_][j_];    \
  const float pNv = sN[par_][j_];                                            \
  const float r1s = dpp_shl1_f(r1);                                          \
  const float d5  = r1s * scale;                                             \
  const float g0 = r0 * pKv, g1 = r1 * pAv, g2 = r2 * pKv;                   \
  const float g3 = r3 * pBv, g4 = r4 * pKv, g5 = d5 * pNv;                   \
  const float n0 = g0 + g1;                                                  \
  const float n1 = __builtin_fmaf(skAp, g3, g1 + g2);                        \
  const float n2 = g2 + g3;                                                  \
  const float n3 = __builtin_fmaf(skBp, g5, g3 + g4);                        \
  const float n4 = g4 + g5;                                                  \
  r0 = n0; r1 = n1; r2 = n2; r3 = n3; r4 = n4;                               \
} while (0)

// Batched refill of set (w+1)&1 with rows 4w+4..4w+7 (compile-time).
#define AREFILL(w_) do {                                                     \
  _Pragma("unroll")                                                          \
  for (int j = 0; j < 4; ++j) {                                              \
    const int rr = 4 * (w_) + 4 + j;                                         \
    const float* nr = (rr < 32) ? (pc + rr * C_DIM)                          \
                                : (pn + (rr - 32) * C_DIM);                  \
    sA[((w_) + 1) & 1][j] = nr[tgA];                                         \
    sB[((w_) + 1) & 1][j] = nr[tgB];                                         \
    sK[((w_) + 1) & 1][j] = nr[0];                                           \
  }                                                                          \
} while (0)

#define BREFILL(w_) do {                                                     \
  _Pragma("unroll")                                                          \
  for (int j = 0; j < 4; ++j) {                                              \
    const int rr = 4 * (w_) + 4 + j;                                         \
    const float* nr = (rr < 32) ? (pc + rr * C_DIM)                          \
                                : (pn + (rr - 32) * C_DIM);                  \
    sA[((w_) + 1) & 1][j] = nr[tgA];                                         \
    sB[((w_) + 1) & 1][j] = nr[tgB];                                         \
    sK[((w_) + 1) & 1][j] = nr[0];                                           \
    sN[((w_) + 1) & 1][j] = nr[tgAn];                                        \
  }                                                                          \
} while (0)

// FAST windows: batch loads, then 4 pure-VALU steps, then exchange.
#define AWIN(w_) do {                                                        \
  AREFILL(w_);                                                               \
  AMATH((w_) & 1, 0); AMATH((w_) & 1, 1);                                    \
  AMATH((w_) & 1, 2); AMATH((w_) & 1, 3);                                    \
  AEXCH();                                                                   \
} while (0)

#define BWIN(w_) do {                                                        \
  BREFILL(w_);                                                               \
  BMATH((w_) & 1, 0); BMATH((w_) & 1, 1);                                    \
  BMATH((w_) & 1, 2); BMATH((w_) & 1, 3);                                    \
  BEXCH();                                                                   \
} while (0)

// Guarded single steps for tail phases (refill hoisted outside guard).
#define ASTEP_G(k_, cond_) do {                                              \
  const int kn_ = (k_) + 4;                                                  \
  {                                                                          \
    const float* nr = (kn_ < 32) ? (pc + kn_ * C_DIM)                        \
                                 : (pn + (kn_ - 32) * C_DIM);                \
    sA[(kn_ >> 2) & 1][kn_ & 3] = nr[tgA];                                   \
    sB[(kn_ >> 2) & 1][kn_ & 3] = nr[tgB];                                   \
    sK[(kn_ >> 2) & 1][kn_ & 3] = nr[0];                                     \
  }                                                                          \
  if (cond_) {                                                               \
    AMATH(((k_) >> 2) & 1, (k_) & 3);                                        \
    if (((k_) & 3) == 3) { AEXCH(); }                                        \
  }                                                                          \
} while (0)

#define BSTEP_G(k_, cond_) do {                                              \
  const int kn_ = (k_) + 4;                                                  \
  {                                                                          \
    const float* nr = (kn_ < 32) ? (pc + kn_ * C_DIM)                        \
                                 : (pn + (kn_ - 32) * C_DIM);                \
    sA[(kn_ >> 2) & 1][kn_ & 3] = nr[tgA];                                   \
    sB[(kn_ >> 2) & 1][kn_ & 3] = nr[tgB];                                   \
    sK[(kn_ >> 2) & 1][kn_ & 3] = nr[0];                                     \
    sN[(kn_ >> 2) & 1][kn_ & 3] = nr[tgAn];                                  \
  }                                                                          \
  if (cond_) {                                                               \
    BMATH(((k_) >> 2) & 1, (k_) & 3);                                        \
    if (((k_) & 3) == 3) { BEXCH(); }                                        \
  }                                                                          \
} while (0)

// Blocks 0..95: ALPHA half (t=0..1023). Blocks 96..191: BETA half
// (rows 2047..1024). R18 structure; consumer LDS reads window-batched.
__global__ __launch_bounds__(256) void ctc_fused_kernel(
    const float* __restrict__ lp, const int* __restrict__ targets,
    const int* __restrict__ in_len, const int* __restrict__ tg_len,
    float* __restrict__ ws)
{
  const int tid = threadIdx.x;
  const int bid = blockIdx.x;
  const int isBeta = (bid >= B_DIM);
  const int b = isBeta ? bid - B_DIM : bid;
  const size_t RSTR = (size_t)B_DIM * C_DIM;       // floats per t-row
  const int Tb = in_len[b];
  const float* base = lp + (size_t)b * C_DIM;

  __shared__ float rows[3][32][C_DIM];             // 48 KB ring of PROBS
  __shared__ float klred[3];

  float klacc = 0.f;                               // producers only

  if (!isBeta) {
    // ================= ALPHA half =================
    const int TbA = (Tb < 1024) ? Tb : 1024;
    int tgA = 0, tgB = 0;
    float skA = 0.f, skB = 0.f;
    float r0 = 0.f, r1 = 0.f, r2 = 0.f, r3 = 0.f, r4 = 0.f;
    int E = SENT;
    float scale = 0.f;
    float sA[2][4], sB[2][4], sK[2][4];

    if (tid < 64) {
      const int l = tid;
      tgA = targets[b * L_DIM + 2 * l];
      tgB = targets[b * L_DIM + 2 * l + 1];
      skA = (l > 0 && tgA != targets[b * L_DIM + 2 * l - 1]) ? 1.f : 0.f;
      skB = (tgB != tgA) ? 1.f : 0.f;
      if (l == 0) {
        r0 = __builtin_amdgcn_exp2f(base[0]   * LOG2E);
        r1 = __builtin_amdgcn_exp2f(base[tgA] * LOG2E);
        E = 0;
      }
    } else {
      const int ptid = tid - 64;
      #pragma unroll
      for (int i = 0; i < 11; ++i) {
        const int task = i * 192 + ptid;
        if (task < 2048) {
          const int row = task >> 5;
          const int c4  = task & 31;
          const int t   = 1 + row;
          const float4 v = *(const float4*)(base + (size_t)t * RSTR + c4 * 4);
          float4 w;
          w.x = __builtin_amdgcn_exp2f(v.x * LOG2E);
          w.y = __builtin_amdgcn_exp2f(v.y * LOG2E);
          w.z = __builtin_amdgcn_exp2f(v.z * LOG2E);
          w.w = __builtin_amdgcn_exp2f(v.w * LOG2E);
          *(float4*)&rows[row >> 5][row & 31][c4 * 4] = w;
          if (t < Tb) {
            float s = v.x + v.y + v.z + v.w;
            if (c4 == 0) s -= v.x;
            klacc += s;
          }
        }
      }
      if (ptid < 32 && 0 < Tb) {
        const float4 v = *(const float4*)(base + ptid * 4);
        float s = v.x + v.y + v.z + v.w;
        if (ptid == 0) s -= v.x;
        klacc += s;
      }
    }
    __syncthreads();

    if (tid < 64) {
      #pragma unroll
      for (int j = 0; j < 4; ++j) {
        sA[0][j] = rows[0][j][tgA]; sB[0][j] = rows[0][j][tgB];
        sK[0][j] = rows[0][j][0];
      }
      AEXCH();                                     // initial frame exchange
    }
    float* pc = &rows[0][0][0];
    float* pn = &rows[1][0][0];
    float* pf = &rows[2][0][0];

    for (int p = 0; p < NPH; ++p) {
      if (tid < 64) {
        if (32 * p + 33 <= TbA) {
          #pragma unroll
          for (int w = 0; w < 8; ++w) { AWIN(w); }
        } else {
          #pragma unroll
          for (int k = 0; k < 32; ++k) {
            const int t = 1 + 32 * p + k;
            ASTEP_G(k, t < TbA);
          }
        }
      } else {
        const int ptid = tid - 64;
        const int t0 = 65 + 32 * p;
        if (t0 <= 1023) {
          #pragma unroll
          for (int i = 0; i < 6; ++i) {
            const int task = i * 192 + ptid;
            if (task < 1024) {
              const int row = task >> 5;
              const int c4  = task & 31;
              const int t   = t0 + row;
              if (t <= 1023) {
                const float4 v = *(const float4*)(base + (size_t)t * RSTR + c4 * 4);
                float4 w;
                w.x = __builtin_amdgcn_exp2f(v.x * LOG2E);
                w.y = __builtin_amdgcn_exp2f(v.y * LOG2E);
                w.z = __builtin_amdgcn_exp2f(v.z * LOG2E);
                w.w = __builtin_amdgcn_exp2f(v.w * LOG2E);
                *(float4*)&pf[row * C_DIM + c4 * 4] = w;
                if (t < Tb) {
                  float s = v.x + v.y + v.z + v.w;
                  if (c4 == 0) s -= v.x;
                  klacc += s;
                }
              }
            }
          }
        }
      }
      __syncthreads();
      float* tmp = pc; pc = pn; pn = pf; pf = tmp;
    }

    if (tid < 64) {
      const int l = tid;
      const float Ef = (float)E;
      float* dst = ws + AOFF + b * 257;
      dst[4 * l + 0] = __builtin_amdgcn_logf(r0) + Ef;
      dst[4 * l + 1] = __builtin_amdgcn_logf(r1) + Ef;
      dst[4 * l + 2] = __builtin_amdgcn_logf(r2) + Ef;
      dst[4 * l + 3] = __builtin_amdgcn_logf(r3) + Ef;
      if (l == 63) dst[256] = __builtin_amdgcn_logf(r4) + Ef;
    } else {
      float tot = klacc;
      tot += __shfl_xor(tot, 1, 64);  tot += __shfl_xor(tot, 2, 64);
      tot += __shfl_xor(tot, 4, 64);  tot += __shfl_xor(tot, 8, 64);
      tot += __shfl_xor(tot, 16, 64); tot += __shfl_xor(tot, 32, 64);
      if ((tid & 63) == 0) klred[(tid >> 6) - 1] = tot;
    }
    __syncthreads();
    if (tid == 0) ws[KLA + b] = klred[0] + klred[1] + klred[2];

  } else {
    // ================= BETA half =================
    int tgA = 0, tgB = 0, tgAn = 0;
    float skAp = 0.f, skBp = 0.f;
    float r0 = 0.f, r1 = 0.f, r2 = 0.f, r3 = 0.f, r4 = 0.f;
    int E = SENT;
    float scale = 0.f;
    float sA[2][4], sB[2][4], sK[2][4], sN[2][4];

    if (tid < 64) {
      const int l = tid;
      tgA = targets[b * L_DIM + 2 * l];
      tgB = targets[b * L_DIM + 2 * l + 1];
      const int nidx = (l < 63) ? (2 * l + 2) : (2 * l);
      tgAn = targets[b * L_DIM + nidx];
      skAp = (tgB != tgA) ? 1.f : 0.f;
      skBp = (l < 63 && tgAn != tgB) ? 1.f : 0.f;
      const int Lt = tg_len[b];
      const int s0 = 4 * l;
      r0 = (s0 == 2 * Lt || s0 == 2 * Lt - 1) ? 1.f : 0.f;
      r1 = (s0 + 1 == 2 * Lt || s0 + 1 == 2 * Lt - 1) ? 1.f : 0.f;
      r2 = (s0 + 2 == 2 * Lt || s0 + 2 == 2 * Lt - 1) ? 1.f : 0.f;
      r3 = (s0 + 3 == 2 * Lt || s0 + 3 == 2 * Lt - 1) ? 1.f : 0.f;
      r4 = (s0 + 4 == 2 * Lt || s0 + 4 == 2 * Lt - 1) ? 1.f : 0.f;
      E = (r0 + r1 + r2 + r3 + r4 > 0.f) ? 0 : SENT;
    } else {
      const int ptid = tid - 64;
      #pragma unroll
      for (int i = 0; i < 11; ++i) {
        const int task = i * 192 + ptid;
        if (task < 2048) {
          const int row = task >> 5;                // j = 0..63
          const int c4  = task & 31;
          const int t   = 2047 - row;
          const float4 v = *(const float4*)(base + (size_t)t * RSTR + c4 * 4);
          float4 w;
          w.x = __builtin_amdgcn_exp2f(v.x * LOG2E);
          w.y = __builtin_amdgcn_exp2f(v.y * LOG2E);
          w.z = __builtin_amdgcn_exp2f(v.z * LOG2E);
          w.w = __builtin_amdgcn_exp2f(v.w * LOG2E);
          *(float4*)&rows[row >> 5][row & 31][c4 * 4] = w;
          if (t < Tb) {
            float s = v.x + v.y + v.z + v.w;
            if (c4 == 0) s -= v.x;
            klacc += s;
          }
        }
      }
    }
    __syncthreads();

    if (tid < 64) {
      #pragma unroll
      for (int j = 0; j < 4; ++j) {
        sA[0][j] = rows[0][j][tgA]; sB[0][j] = rows[0][j][tgB];
        sK[0][j] = rows[0][j][0];   sN[0][j] = rows[0][j][tgAn];
      }
      BEXCH();                                     // initial frame exchange
    }
    float* pc = &rows[0][0][0];
    float* pn = &rows[1][0][0];
    float* pf = &rows[2][0][0];

    for (int p = 0; p < NPH; ++p) {
      if (tid < 64) {
        const int rmax = 2047 - 32 * p;
        const int rmin = rmax - 31;
        if (rmax < Tb) {
          #pragma unroll
          for (int w = 0; w < 8; ++w) { BWIN(w); }
        } else if (rmin < Tb) {
          #pragma unroll
          for (int k = 0; k < 32; ++k) {
            const int r = 2047 - 32 * p - k;
            BSTEP_G(k, r < Tb);
          }
        }
      } else {
        const int ptid = tid - 64;
        const int t0 = 1983 - 32 * p;
        if (t0 >= 1024) {
          #pragma unroll
          for (int i = 0; i < 6; ++i) {
            const int task = i * 192 + ptid;
            if (task < 1024) {
              const int row = task >> 5;
              const int c4  = task & 31;
              const int t   = t0 - row;
              if (t >= 1024) {
                const float4 v = *(const float4*)(base + (size_t)t * RSTR + c4 * 4);
                float4 w;
                w.x = __builtin_amdgcn_exp2f(v.x * LOG2E);
                w.y = __builtin_amdgcn_exp2f(v.y * LOG2E);
                w.z = __builtin_amdgcn_exp2f(v.z * LOG2E);
                w.w = __builtin_amdgcn_exp2f(v.w * LOG2E);
                *(float4*)&pf[row * C_DIM + c4 * 4] = w;
                if (t < Tb) {
                  float s = v.x + v.y + v.z + v.w;
                  if (c4 == 0) s -= v.x;
                  klacc += s;
                }
              }
            }
          }
        }
      }
      __syncthreads();
      float* tmp = pc; pc = pn; pn = pf; pf = tmp;
    }

    if (tid < 64) {
      const int l = tid;
      const float Ef = (float)E;
      float* dst = ws + BOFF + b * 257;
      dst[4 * l + 0] = __builtin_amdgcn_logf(r0) + Ef;
      dst[4 * l + 1] = __builtin_amdgcn_logf(r1) + Ef;
      dst[4 * l + 2] = __builtin_amdgcn_logf(r2) + Ef;
      dst[4 * l + 3] = __builtin_amdgcn_logf(r3) + Ef;
      if (l == 63) dst[256] = __builtin_amdgcn_logf(r4) + Ef;
    } else {
      float tot = klacc;
      tot += __shfl_xor(tot, 1, 64);  tot += __shfl_xor(tot, 2, 64);
      tot += __shfl_xor(tot, 4, 64);  tot += __shfl_xor(tot, 8, 64);
      tot += __shfl_xor(tot, 16, 64); tot += __shfl_xor(tot, 32, 64);
      if ((tid & 63) == 0) klred[(tid >> 6) - 1] = tot;
    }
    __syncthreads();
    if (tid == 0) ws[KLB + b] = klred[0] + klred[1] + klred[2];
  }
}

// Per-sample combine: ll = logsumexp_s(alpha_log2[s] + beta_log2[s]); loss.
__global__ __launch_bounds__(64) void ctc_combine_kernel(
    const float* __restrict__ ws_in, const int* __restrict__ in_len,
    float* __restrict__ ws_out)
{
  const int b = blockIdx.x;
  const int l = threadIdx.x;
  const float* a  = ws_in + AOFF + b * 257;
  const float* bb = ws_in + BOFF + b * 257;
  float x0 = a[4 * l + 0] + bb[4 * l + 0];
  float x1 = a[4 * l + 1] + bb[4 * l + 1];
  float x2 = a[4 * l + 2] + bb[4 * l + 2];
  float x3 = a[4 * l + 3] + bb[4 * l + 3];
  float x4 = (l == 63) ? (a[256] + bb[256]) : -3.0e38f;
  float m = fmaxf(fmaxf(fmaxf(x0, x1), fmaxf(x2, x3)), x4);
  m = fmaxf(m, __shfl_xor(m, 1, 64));  m = fmaxf(m, __shfl_xor(m, 2, 64));
  m = fmaxf(m, __shfl_xor(m, 4, 64));  m = fmaxf(m, __shfl_xor(m, 8, 64));
  m = fmaxf(m, __shfl_xor(m, 16, 64)); m = fmaxf(m, __shfl_xor(m, 32, 64));
  const float ms = fmaxf(m, -1.0e37f);
  float s = __builtin_amdgcn_exp2f(x0 - ms) + __builtin_amdgcn_exp2f(x1 - ms)
          + __builtin_amdgcn_exp2f(x2 - ms) + __builtin_amdgcn_exp2f(x3 - ms)
          + __builtin_amdgcn_exp2f(x4 - ms);
  s += __shfl_xor(s, 1, 64);  s += __shfl_xor(s, 2, 64);
  s += __shfl_xor(s, 4, 64);  s += __shfl_xor(s, 8, 64);
  s += __shfl_xor(s, 16, 64); s += __shfl_xor(s, 32, 64);
  if (l == 0) {
    float ctc = 0.f;
    if (s > 0.f && m > -1.0e30f) {
      ctc = -((ms + __builtin_amdgcn_logf(s)) * LN2);
    }
    const int Tb = in_len[b];
    const float u    = 1.0f / (C_DIM - 1);
    const float logu = -4.8441870864585910f;       // log(1/127)
    const float kls  = ws_in[KLA + b] + ws_in[KLB + b];
    const float klmean = logu - u * kls / (float)Tb;
    ws_out[LOSS + b] = (1.0f - SMOOTH) * ctc + SMOOTH * klmean;
  }
}

__global__ __launch_bounds__(128) void ctc_mean_kernel(
    const float* __restrict__ ws, float* __restrict__ out)
{
  __shared__ float red[128];
  const int tid = threadIdx.x;
  red[tid] = (tid < B_DIM) ? ws[LOSS + tid] : 0.f;
  __syncthreads();
  for (int off = 64; off > 0; off >>= 1) {
    if (tid < off) red[tid] += red[tid + off];
    __syncthreads();
  }
  if (tid == 0) out[0] = red[0] / (float)B_DIM;
}

extern "C" void kernel_launch(void* const* d_in, const int* in_sizes, int n_in,
                              void* d_out, int out_size, void* d_ws, size_t ws_size,
                              hipStream_t stream) {
  const float* lp      = (const float*)d_in[0];
  const int* targets   = (const int*)d_in[1];
  const int* in_len    = (const int*)d_in[2];
  const int* tg_len    = (const int*)d_in[3];
  float* ws  = (float*)d_ws;
  float* out = (float*)d_out;

  hipLaunchKernelGGL(ctc_fused_kernel, dim3(2 * B_DIM), dim3(256), 0, stream,
                     lp, targets, in_len, tg_len, ws);
  hipLaunchKernelGGL(ctc_combine_kernel, dim3(B_DIM), dim3(64), 0, stream,
                     ws, in_len, ws);
  hipLaunchKernelGGL(ctc_mean_kernel, dim3(1), dim3(128), 0, stream,
                     ws, out);
}